// Round 3
// baseline (975.324 us; speedup 1.0000x reference)
//
#include <hip/hip_runtime.h>
#include <math.h>

#define N_NODES 100000
#define N_EDGES 1250000
#define NGRAPH 256
#define IN_DIM 8
#define DIM 64
#define BN_EPS 1e-5f

#define NBLK_SCAN 391  // ceil(100000/256)

typedef unsigned short bf16_t;

static __device__ inline float bf2f(bf16_t u) {
    return __uint_as_float(((unsigned int)u) << 16);
}
static __device__ inline bf16_t f2bf(float f) {
    unsigned int b = __float_as_uint(f);
    b += 0x7fffu + ((b >> 16) & 1u);
    return (bf16_t)(b >> 16);
}

// ---------------- init: deg=1 (self-loop weight), counts=0 ----------------

__global__ void k_init(float* __restrict__ deg, int* __restrict__ counts) {
    int i = blockIdx.x * 256 + threadIdx.x;
    if (i < N_NODES) { deg[i] = 1.0f; counts[i] = 0; }
}

// ---------------- fused degree-sum + in-degree histogram ----------------

__global__ void k_degcnt(const int* __restrict__ dst, const float* __restrict__ edge_attr,
                         float* __restrict__ deg, int* __restrict__ counts) {
    int e = blockIdx.x * 256 + threadIdx.x;
    if (e < N_EDGES) {
        int d = dst[e];
        atomicAdd(&deg[d], edge_attr[2 * e + 1]);
        atomicAdd(&counts[d], 1);
    }
}

__global__ void k_dinv(float* __restrict__ deg, float* __restrict__ selfnorm) {
    int i = blockIdx.x * 256 + threadIdx.x;
    if (i < N_NODES) {
        float d = deg[i];
        float r = (d > 0.0f) ? rsqrtf(d) : 0.0f;
        deg[i] = r;
        selfnorm[i] = r * r;
    }
}

// ---------------- CSR build (counting sort by dst) ----------------

__global__ void k_blockreduce(const int* __restrict__ counts, int* __restrict__ blocksums) {
    __shared__ int sh[256];
    int t = threadIdx.x;
    int i = blockIdx.x * 256 + t;
    sh[t] = (i < N_NODES) ? counts[i] : 0;
    __syncthreads();
    for (int off = 128; off > 0; off >>= 1) {
        if (t < off) sh[t] += sh[t + off];
        __syncthreads();
    }
    if (t == 0) blocksums[blockIdx.x] = sh[0];
}

__global__ void k_scanblocksums(int* __restrict__ blocksums) {
    __shared__ int sh[512];
    int t = threadIdx.x;
    int v = (t < NBLK_SCAN) ? blocksums[t] : 0;
    sh[t] = v;
    __syncthreads();
    for (int off = 1; off < 512; off <<= 1) {
        int add = (t >= off) ? sh[t - off] : 0;
        __syncthreads();
        sh[t] += add;
        __syncthreads();
    }
    if (t < NBLK_SCAN) blocksums[t] = sh[t] - v;  // exclusive
}

__global__ void k_blockscan(const int* __restrict__ counts, const int* __restrict__ blocksums,
                            int* __restrict__ offsets, int* __restrict__ cursor) {
    __shared__ int sh[256];
    int t = threadIdx.x;
    int i = blockIdx.x * 256 + t;
    int v = (i < N_NODES) ? counts[i] : 0;
    sh[t] = v;
    __syncthreads();
    for (int off = 1; off < 256; off <<= 1) {
        int add = (t >= off) ? sh[t - off] : 0;
        __syncthreads();
        sh[t] += add;
        __syncthreads();
    }
    int excl = sh[t] - v + blocksums[blockIdx.x];
    if (i < N_NODES) { offsets[i] = excl; cursor[i] = excl; }
    if (i == N_NODES - 1) offsets[N_NODES] = excl + v;  // == E
}

__global__ void k_fill(const int* __restrict__ src, const int* __restrict__ dst,
                       const float* __restrict__ edge_attr, const float* __restrict__ dinv,
                       int* __restrict__ cursor, int2* __restrict__ csr) {
    int e = blockIdx.x * 256 + threadIdx.x;
    if (e >= N_EDGES) return;
    int s = src[e], d = dst[e];
    float w = edge_attr[2 * e + 1];
    int pos = atomicAdd(&cursor[d], 1);
    float nv = dinv[s] * w * dinv[d];
    csr[pos] = make_int2(s, __float_as_int(nv));
}

// ------- matmul: t[N,64] = bn_affine(h)[N,K] @ W[K,64], 32 rows/block, bf16 out -------

template <int K, bool AFFINE, typename TIN>
__global__ void k_matmul(const TIN* __restrict__ h, const float* __restrict__ W,
                         const float* __restrict__ stats, const float* __restrict__ gamma,
                         const float* __restrict__ beta, bf16_t* __restrict__ out) {
    __shared__ float Wsh[K * 64];
    __shared__ float hsh[32 * K];
    __shared__ float scs[K], shs[K];
    int tid = threadIdx.x;
    if (AFFINE) {
        if (tid < K) {
            const float invn = 1.0f / (float)N_NODES;
            float mu = stats[tid] * invn;
            float var = stats[64 + tid] * invn - mu * mu;
            float rs = rsqrtf(var + BN_EPS);
            float sc = gamma[tid] * rs;
            scs[tid] = sc;
            shs[tid] = beta[tid] - sc * mu;
        }
    }
    for (int i = tid; i < K * 64; i += 256) Wsh[i] = W[i];
    __syncthreads();
    int row0 = blockIdx.x * 32;
    if (sizeof(TIN) == 2) {  // bf16 input with affine
        const ushort2* h2 = (const ushort2*)((const bf16_t*)h + row0 * K);
        for (int i = tid; i < 32 * K / 2; i += 256) {
            ushort2 u = h2[i];
            int base = 2 * i;
            int kk = base & (K - 1);
            float sc0 = AFFINE ? scs[kk] : 1.0f, sh0 = AFFINE ? shs[kk] : 0.0f;
            float sc1 = AFFINE ? scs[kk + 1] : 1.0f, sh1 = AFFINE ? shs[kk + 1] : 0.0f;
            hsh[base] = bf2f(u.x) * sc0 + sh0;
            hsh[base + 1] = bf2f(u.y) * sc1 + sh1;
        }
    } else {  // fp32 input, no affine (layer 0)
        const float* hf = (const float*)h + row0 * K;
        for (int i = tid; i < 32 * K; i += 256) hsh[i] = hf[i];
    }
    __syncthreads();
    int c = tid & 63, rs = tid >> 6;  // 64 cols x 4 row-slots, 8 rows each
    float acc[8];
#pragma unroll
    for (int j = 0; j < 8; ++j) acc[j] = 0.0f;
    for (int k = 0; k < K; ++k) {
        float w = Wsh[k * 64 + c];
#pragma unroll
        for (int j = 0; j < 8; ++j) acc[j] += hsh[(rs * 8 + j) * K + k] * w;
    }
#pragma unroll
    for (int j = 0; j < 8; ++j) out[(row0 + rs * 8 + j) * 64 + c] = f2bf(acc[j]);
}

// ------- CSR gather + bias + relu + fused BN stats, bf16 in/out, grid-stride -------

__global__ void k_gather(const bf16_t* __restrict__ t, const int* __restrict__ offsets,
                         const int2* __restrict__ csr, const float* __restrict__ selfnorm,
                         const float* __restrict__ bias, bf16_t* __restrict__ hout,
                         float* __restrict__ stats) {
    int tid = threadIdx.x;
    int lane = tid & 63;
    int wv = tid >> 6;
    float bias_l = bias[lane];
    float sum = 0.0f, sumsq = 0.0f;
    int wstride = gridDim.x * 4;
    for (int node = blockIdx.x * 4 + wv; node < N_NODES; node += wstride) {
        int e0 = offsets[node], e1 = offsets[node + 1];
        float acc = selfnorm[node] * bf2f(t[node * 64 + lane]);
        for (int e = e0; e < e1; ++e) {
            int2 p = csr[e];
            acc += __int_as_float(p.y) * bf2f(t[p.x * 64 + lane]);
        }
        acc = fmaxf(acc + bias_l, 0.0f);
        hout[node * 64 + lane] = f2bf(acc);
        sum += acc;
        sumsq += acc * acc;
    }
    __shared__ float s1[256], s2[256];
    s1[tid] = sum; s2[tid] = sumsq;
    __syncthreads();
    if (tid < 64) {
        atomicAdd(&stats[tid], s1[tid] + s1[tid + 64] + s1[tid + 128] + s1[tid + 192]);
        atomicAdd(&stats[64 + tid], s2[tid] + s2[tid + 64] + s2[tid + 128] + s2[tid + 192]);
    }
}

// ---------------- pooling over sorted batch (run-length local accumulation) ----------------

__global__ void k_pool(const int* __restrict__ batch, const bf16_t* __restrict__ h,
                       float* __restrict__ pooled, int* __restrict__ gcount) {
    const int ROWS = 512;
    int c = threadIdx.x & 63;
    int wsub = threadIdx.x >> 6;  // 0..3
    int start = blockIdx.x * ROWS;
    int end = start + ROWS; if (end > N_NODES) end = N_NODES;
    int cur = -1, cnt = 0;
    float acc = 0.0f;
    for (int r = start + wsub; r < end; r += 4) {
        int g = batch[r];
        float v = bf2f(h[r * 64 + c]);
        if (g != cur) {
            if (cur >= 0) {
                atomicAdd(&pooled[cur * 64 + c], acc);
                if (c == 0) atomicAdd(&gcount[cur], cnt);
            }
            cur = g; acc = 0.0f; cnt = 0;
        }
        acc += v; cnt += 1;
    }
    if (cur >= 0) {
        atomicAdd(&pooled[cur * 64 + c], acc);
        if (c == 0) atomicAdd(&gcount[cur], cnt);
    }
}

// ------- head: BN affine from raw stats folded via counts, mlp, log_softmax -------

__global__ void k_head(const float* __restrict__ pooled, const int* __restrict__ gcount,
                       const float* __restrict__ stats, const float* __restrict__ gamma,
                       const float* __restrict__ beta, const float* __restrict__ w1,
                       const float* __restrict__ b1, const float* __restrict__ w2,
                       const float* __restrict__ b2, float* __restrict__ out) {
    __shared__ float p[64];
    __shared__ float hid[64];
    __shared__ float o[2];
    int g = blockIdx.x, c = threadIdx.x;
    const float invn = 1.0f / (float)N_NODES;
    float mu = stats[c] * invn;
    float var = stats[64 + c] * invn - mu * mu;
    float rs = rsqrtf(var + BN_EPS);
    float sc = gamma[c] * rs;
    float sh = beta[c] - sc * mu;
    p[c] = sc * pooled[g * 64 + c] + (float)gcount[g] * sh;
    __syncthreads();
    float acc = b1[c];
#pragma unroll
    for (int k = 0; k < 64; ++k) acc += p[k] * w1[k * 64 + c];
    hid[c] = fmaxf(acc, 0.0f);
    __syncthreads();
    if (c < 2) {
        float a = b2[c];
#pragma unroll
        for (int k = 0; k < 64; ++k) a += hid[k] * w2[k * 2 + c];
        o[c] = a;
    }
    __syncthreads();
    if (c == 0) {
        float m = fmaxf(o[0], o[1]);
        float l = m + logf(expf(o[0] - m) + expf(o[1] - m));
        out[g * 2 + 0] = o[0] - l;
        out[g * 2 + 1] = o[1] - l;
    }
}

extern "C" void kernel_launch(void* const* d_in, const int* in_sizes, int n_in,
                              void* d_out, int out_size, void* d_ws, size_t ws_size,
                              hipStream_t stream) {
    const float* x        = (const float*)d_in[0];
    const int*   ei       = (const int*)d_in[1];
    const int*   batch    = (const int*)d_in[2];
    const float* edge_attr= (const float*)d_in[3];
    const float* W0       = (const float*)d_in[4];
    const float* b0       = (const float*)d_in[5];
    const float* Ws       = (const float*)d_in[6];
    const float* bs       = (const float*)d_in[7];
    const float* gammas   = (const float*)d_in[8];
    const float* betas    = (const float*)d_in[9];
    const float* lin1_w   = (const float*)d_in[10];
    const float* lin1_b   = (const float*)d_in[11];
    const float* lin2_w   = (const float*)d_in[12];
    const float* lin2_b   = (const float*)d_in[13];
    float* out = (float*)d_out;

    const int* src = ei;
    const int* dst = ei + N_EDGES;

    // workspace layout (float units)
    float* ws = (float*)d_ws;
    float*  selfnorm = ws;                                  // 100000
    int*    offsets  = (int*)(ws + 100000);                 // 100002 (pad even)
    int2*   csr      = (int2*)(ws + 200002);                // 2*1250000 (8B-aligned)
    bf16_t* tbuf     = (bf16_t*)(ws + 2700002);             // N*64 bf16 = 3200000 fl
    bf16_t* hbuf     = (bf16_t*)(ws + 5900002);             // N*64 bf16 = 3200000 fl
    float*  stats    = ws + 9100002;                        // 3*128
    float*  pooled   = stats + 384;                         // 16384
    int*    gcount   = (int*)(pooled + NGRAPH * 64);        // 256
    // transient CSR-build aliases inside tbuf (dead before first tbuf write)
    float* dinv      = (float*)tbuf;                        // 100000
    int*   counts    = (int*)((float*)tbuf + 100000);       // 100000
    int*   cursor    = (int*)((float*)tbuf + 200000);       // 100000
    int*   blocksums = (int*)((float*)tbuf + 300000);       // 512

    const int nblk_n = (N_NODES + 255) / 256;   // 391
    const int nblk_e = (N_EDGES + 255) / 256;
    const int nblk_mm = N_NODES / 32;           // 3125
    const int nblk_pool = (N_NODES + 511) / 512;

    // zero stats/pooled/gcount in one shot (contiguous)
    hipMemsetAsync(stats, 0, (384 + NGRAPH * 64 + NGRAPH) * sizeof(float), stream);

    // ---- degree / dinv / selfnorm + CSR build ----
    k_init<<<nblk_n, 256, 0, stream>>>(dinv, counts);
    k_degcnt<<<nblk_e, 256, 0, stream>>>(dst, edge_attr, dinv, counts);
    k_dinv<<<nblk_n, 256, 0, stream>>>(dinv, selfnorm);
    k_blockreduce<<<NBLK_SCAN, 256, 0, stream>>>(counts, blocksums);
    k_scanblocksums<<<1, 512, 0, stream>>>(blocksums);
    k_blockscan<<<NBLK_SCAN, 256, 0, stream>>>(counts, blocksums, offsets, cursor);
    k_fill<<<nblk_e, 256, 0, stream>>>(src, dst, edge_attr, dinv, cursor, csr);

    // ---- layer 0 (K=8, fp32 in, no affine) ----
    k_matmul<IN_DIM, false, float><<<nblk_mm, 256, 0, stream>>>(
        x, W0, nullptr, nullptr, nullptr, tbuf);
    k_gather<<<1024, 256, 0, stream>>>(tbuf, offsets, csr, selfnorm, b0, hbuf, stats);

    // ---- layers 1..2 (K=64, bf16 in, BN affine fused into matmul load) ----
    for (int l = 0; l < 2; ++l) {
        k_matmul<DIM, true, bf16_t><<<nblk_mm, 256, 0, stream>>>(
            hbuf, Ws + l * 64 * 64, stats + l * 128, gammas + l * 64, betas + l * 64, tbuf);
        k_gather<<<1024, 256, 0, stream>>>(tbuf, offsets, csr, selfnorm, bs + l * 64, hbuf,
                                           stats + (l + 1) * 128);
    }

    // ---- pool (BN affine folded into head via counts) + head ----
    k_pool<<<nblk_pool, 256, 0, stream>>>(batch, hbuf, pooled, gcount);
    k_head<<<NGRAPH, 64, 0, stream>>>(pooled, gcount, stats + 2 * 128,
                                      gammas + 2 * 64, betas + 2 * 64,
                                      lin1_w, lin1_b, lin2_w, lin2_b, out);
}

// Round 4
// 851.867 us; speedup vs baseline: 1.1449x; 1.1449x over previous
//
#include <hip/hip_runtime.h>
#include <math.h>

#define N_NODES 100000
#define N_EDGES 1250000
#define NGRAPH 256
#define IN_DIM 8
#define DIM 64
#define BN_EPS 1e-5f

#define NBLK_SCAN 391  // ceil(100000/256)

typedef unsigned short bf16_t;

static __device__ inline float bf2f(bf16_t u) {
    return __uint_as_float(((unsigned int)u) << 16);
}
static __device__ inline bf16_t f2bf(float f) {
    unsigned int b = __float_as_uint(f);
    b += 0x7fffu + ((b >> 16) & 1u);
    return (bf16_t)(b >> 16);
}

// ---------------- init: deg=1 (self-loop weight), counts=0 ----------------

__global__ void k_init(float* __restrict__ deg, int* __restrict__ counts) {
    int i = blockIdx.x * 256 + threadIdx.x;
    if (i < N_NODES) { deg[i] = 1.0f; counts[i] = 0; }
}

// ---------------- fused degree-sum + in-degree histogram ----------------

__global__ void k_degcnt(const int* __restrict__ dst, const float2* __restrict__ edge_attr,
                         float* __restrict__ deg, int* __restrict__ counts) {
    int e = blockIdx.x * 256 + threadIdx.x;
    if (e < N_EDGES) {
        int d = dst[e];
        atomicAdd(&deg[d], edge_attr[e].y);
        atomicAdd(&counts[d], 1);
    }
}

__global__ void k_dinv(float* __restrict__ deg, float* __restrict__ selfnorm) {
    int i = blockIdx.x * 256 + threadIdx.x;
    if (i < N_NODES) {
        float d = deg[i];
        float r = (d > 0.0f) ? rsqrtf(d) : 0.0f;
        deg[i] = r;
        selfnorm[i] = r * r;
    }
}

// ---------------- CSR build (counting sort by dst) ----------------

__global__ void k_blockreduce(const int* __restrict__ counts, int* __restrict__ blocksums) {
    __shared__ int sh[256];
    int t = threadIdx.x;
    int i = blockIdx.x * 256 + t;
    sh[t] = (i < N_NODES) ? counts[i] : 0;
    __syncthreads();
    for (int off = 128; off > 0; off >>= 1) {
        if (t < off) sh[t] += sh[t + off];
        __syncthreads();
    }
    if (t == 0) blocksums[blockIdx.x] = sh[0];
}

__global__ void k_scanblocksums(int* __restrict__ blocksums) {
    __shared__ int sh[512];
    int t = threadIdx.x;
    int v = (t < NBLK_SCAN) ? blocksums[t] : 0;
    sh[t] = v;
    __syncthreads();
    for (int off = 1; off < 512; off <<= 1) {
        int add = (t >= off) ? sh[t - off] : 0;
        __syncthreads();
        sh[t] += add;
        __syncthreads();
    }
    if (t < NBLK_SCAN) blocksums[t] = sh[t] - v;  // exclusive
}

__global__ void k_blockscan(const int* __restrict__ counts, const int* __restrict__ blocksums,
                            int* __restrict__ offsets, int* __restrict__ cursor) {
    __shared__ int sh[256];
    int t = threadIdx.x;
    int i = blockIdx.x * 256 + t;
    int v = (i < N_NODES) ? counts[i] : 0;
    sh[t] = v;
    __syncthreads();
    for (int off = 1; off < 256; off <<= 1) {
        int add = (t >= off) ? sh[t - off] : 0;
        __syncthreads();
        sh[t] += add;
        __syncthreads();
    }
    int excl = sh[t] - v + blocksums[blockIdx.x];
    if (i < N_NODES) { offsets[i] = excl; cursor[i] = excl; }
    if (i == N_NODES - 1) offsets[N_NODES] = excl + v;  // == E
}

__global__ void k_fill(const int* __restrict__ src, const int* __restrict__ dst,
                       const float2* __restrict__ edge_attr, const float* __restrict__ dinv,
                       int* __restrict__ cursor, int2* __restrict__ csr) {
    int e = blockIdx.x * 256 + threadIdx.x;
    if (e >= N_EDGES) return;
    int s = src[e], d = dst[e];
    float w = edge_attr[e].y;
    int pos = atomicAdd(&cursor[d], 1);
    float nv = dinv[s] * w * dinv[d];
    csr[pos] = make_int2(s, __float_as_int(nv));
}

// ------- matmul: t[N,64] = bn_affine(h)[N,K] @ W[K,64], 32 rows/block, bf16 out -------

template <int K, bool AFFINE, typename TIN>
__global__ void k_matmul(const TIN* __restrict__ h, const float* __restrict__ W,
                         const float* __restrict__ stats, const float* __restrict__ gamma,
                         const float* __restrict__ beta, bf16_t* __restrict__ out) {
    __shared__ float Wsh[K * 64];
    __shared__ float hsh[32 * K];
    __shared__ float scs[K], shs[K];
    int tid = threadIdx.x;
    if (AFFINE) {
        if (tid < K) {
            const float invn = 1.0f / (float)N_NODES;
            float mu = stats[tid] * invn;
            float var = stats[64 + tid] * invn - mu * mu;
            float rs = rsqrtf(var + BN_EPS);
            float sc = gamma[tid] * rs;
            scs[tid] = sc;
            shs[tid] = beta[tid] - sc * mu;
        }
    }
    for (int i = tid; i < K * 64; i += 256) Wsh[i] = W[i];
    __syncthreads();
    int row0 = blockIdx.x * 32;
    if (sizeof(TIN) == 2) {  // bf16 input with affine
        const ushort2* h2 = (const ushort2*)((const bf16_t*)h + row0 * K);
        for (int i = tid; i < 32 * K / 2; i += 256) {
            ushort2 u = h2[i];
            int base = 2 * i;
            int kk = base & (K - 1);
            float sc0 = AFFINE ? scs[kk] : 1.0f, sh0 = AFFINE ? shs[kk] : 0.0f;
            float sc1 = AFFINE ? scs[kk + 1] : 1.0f, sh1 = AFFINE ? shs[kk + 1] : 0.0f;
            hsh[base] = bf2f(u.x) * sc0 + sh0;
            hsh[base + 1] = bf2f(u.y) * sc1 + sh1;
        }
    } else {  // fp32 input, no affine (layer 0)
        const float* hf = (const float*)h + row0 * K;
        for (int i = tid; i < 32 * K; i += 256) hsh[i] = hf[i];
    }
    __syncthreads();
    int c = tid & 63, rs = tid >> 6;  // 64 cols x 4 row-slots, 8 rows each
    float acc[8];
#pragma unroll
    for (int j = 0; j < 8; ++j) acc[j] = 0.0f;
    for (int k = 0; k < K; ++k) {
        float w = Wsh[k * 64 + c];
#pragma unroll
        for (int j = 0; j < 8; ++j) acc[j] += hsh[(rs * 8 + j) * K + k] * w;
    }
#pragma unroll
    for (int j = 0; j < 8; ++j) out[(row0 + rs * 8 + j) * 64 + c] = f2bf(acc[j]);
}

// ------- CSR gather + bias + relu + fused BN stats, bf16 in/out ----------
// grid-stride over nodes, one wave per node, 4-edge ILP batches

__global__ void k_gather(const bf16_t* __restrict__ t, const int* __restrict__ offsets,
                         const int2* __restrict__ csr, const float* __restrict__ selfnorm,
                         const float* __restrict__ bias, bf16_t* __restrict__ hout,
                         float* __restrict__ stats) {
    int tid = threadIdx.x;
    int lane = tid & 63;
    int wv = tid >> 6;
    float bias_l = bias[lane];
    float sum = 0.0f, sumsq = 0.0f;
    int wstride = gridDim.x * 4;
    for (int node = blockIdx.x * 4 + wv; node < N_NODES; node += wstride) {
        int e0 = offsets[node], e1 = offsets[node + 1];
        float acc = selfnorm[node] * bf2f(t[node * 64 + lane]);
        int e = e0;
        int elast4 = e0 + ((e1 - e0) & ~3);
        for (; e < elast4; e += 4) {
            int2 p0 = csr[e + 0];
            int2 p1 = csr[e + 1];
            int2 p2 = csr[e + 2];
            int2 p3 = csr[e + 3];
            float v0 = bf2f(t[p0.x * 64 + lane]);
            float v1 = bf2f(t[p1.x * 64 + lane]);
            float v2 = bf2f(t[p2.x * 64 + lane]);
            float v3 = bf2f(t[p3.x * 64 + lane]);
            acc = fmaf(__int_as_float(p0.y), v0, acc);
            acc = fmaf(__int_as_float(p1.y), v1, acc);
            acc = fmaf(__int_as_float(p2.y), v2, acc);
            acc = fmaf(__int_as_float(p3.y), v3, acc);
        }
        for (; e < e1; ++e) {
            int2 p = csr[e];
            acc = fmaf(__int_as_float(p.y), bf2f(t[p.x * 64 + lane]), acc);
        }
        acc = fmaxf(acc + bias_l, 0.0f);
        hout[node * 64 + lane] = f2bf(acc);
        sum += acc;
        sumsq += acc * acc;
    }
    __shared__ float s1[256], s2[256];
    s1[tid] = sum; s2[tid] = sumsq;
    __syncthreads();
    if (tid < 64) {
        atomicAdd(&stats[tid], s1[tid] + s1[tid + 64] + s1[tid + 128] + s1[tid + 192]);
        atomicAdd(&stats[64 + tid], s2[tid] + s2[tid + 64] + s2[tid + 128] + s2[tid + 192]);
    }
}

// ---------------- pooling over sorted batch (run-length local accumulation) ----------------

#define POOL_ROWS 128

__global__ void k_pool(const int* __restrict__ batch, const bf16_t* __restrict__ h,
                       float* __restrict__ pooled, int* __restrict__ gcount) {
    int c = threadIdx.x & 63;
    int wsub = threadIdx.x >> 6;  // 0..3
    int start = blockIdx.x * POOL_ROWS;
    int end = start + POOL_ROWS; if (end > N_NODES) end = N_NODES;
    int cur = -1, cnt = 0;
    float acc = 0.0f;
    for (int r = start + wsub; r < end; r += 4) {
        int g = batch[r];
        float v = bf2f(h[r * 64 + c]);
        if (g != cur) {
            if (cur >= 0) {
                atomicAdd(&pooled[cur * 64 + c], acc);
                if (c == 0) atomicAdd(&gcount[cur], cnt);
            }
            cur = g; acc = 0.0f; cnt = 0;
        }
        acc += v; cnt += 1;
    }
    if (cur >= 0) {
        atomicAdd(&pooled[cur * 64 + c], acc);
        if (c == 0) atomicAdd(&gcount[cur], cnt);
    }
}

// ------- head: BN affine from raw stats folded via counts, mlp, log_softmax -------

__global__ void k_head(const float* __restrict__ pooled, const int* __restrict__ gcount,
                       const float* __restrict__ stats, const float* __restrict__ gamma,
                       const float* __restrict__ beta, const float* __restrict__ w1,
                       const float* __restrict__ b1, const float* __restrict__ w2,
                       const float* __restrict__ b2, float* __restrict__ out) {
    __shared__ float p[64];
    __shared__ float hid[64];
    __shared__ float o[2];
    int g = blockIdx.x, c = threadIdx.x;
    const float invn = 1.0f / (float)N_NODES;
    float mu = stats[c] * invn;
    float var = stats[64 + c] * invn - mu * mu;
    float rs = rsqrtf(var + BN_EPS);
    float sc = gamma[c] * rs;
    float sh = beta[c] - sc * mu;
    p[c] = sc * pooled[g * 64 + c] + (float)gcount[g] * sh;
    __syncthreads();
    float acc = b1[c];
#pragma unroll
    for (int k = 0; k < 64; ++k) acc += p[k] * w1[k * 64 + c];
    hid[c] = fmaxf(acc, 0.0f);
    __syncthreads();
    if (c < 2) {
        float a = b2[c];
#pragma unroll
        for (int k = 0; k < 64; ++k) a += hid[k] * w2[k * 2 + c];
        o[c] = a;
    }
    __syncthreads();
    if (c == 0) {
        float m = fmaxf(o[0], o[1]);
        float l = m + logf(expf(o[0] - m) + expf(o[1] - m));
        out[g * 2 + 0] = o[0] - l;
        out[g * 2 + 1] = o[1] - l;
    }
}

extern "C" void kernel_launch(void* const* d_in, const int* in_sizes, int n_in,
                              void* d_out, int out_size, void* d_ws, size_t ws_size,
                              hipStream_t stream) {
    const float* x        = (const float*)d_in[0];
    const int*   ei       = (const int*)d_in[1];
    const int*   batch    = (const int*)d_in[2];
    const float* edge_attr= (const float*)d_in[3];
    const float* W0       = (const float*)d_in[4];
    const float* b0       = (const float*)d_in[5];
    const float* Ws       = (const float*)d_in[6];
    const float* bs       = (const float*)d_in[7];
    const float* gammas   = (const float*)d_in[8];
    const float* betas    = (const float*)d_in[9];
    const float* lin1_w   = (const float*)d_in[10];
    const float* lin1_b   = (const float*)d_in[11];
    const float* lin2_w   = (const float*)d_in[12];
    const float* lin2_b   = (const float*)d_in[13];
    float* out = (float*)d_out;

    const int* src = ei;
    const int* dst = ei + N_EDGES;

    // workspace layout (float units)
    float* ws = (float*)d_ws;
    float*  selfnorm = ws;                                  // 100000
    int*    offsets  = (int*)(ws + 100000);                 // 100002 (pad even)
    int2*   csr      = (int2*)(ws + 200002);                // 2*1250000 (8B-aligned)
    bf16_t* tbuf     = (bf16_t*)(ws + 2700002);             // N*64 bf16 = 3200000 fl
    bf16_t* hbuf     = (bf16_t*)(ws + 5900002);             // N*64 bf16 = 3200000 fl
    float*  stats    = ws + 9100002;                        // 3*128
    float*  pooled   = stats + 384;                         // 16384
    int*    gcount   = (int*)(pooled + NGRAPH * 64);        // 256
    // transient CSR-build aliases inside tbuf (dead before first tbuf write)
    float* dinv      = (float*)tbuf;                        // 100000
    int*   counts    = (int*)((float*)tbuf + 100000);       // 100000
    int*   cursor    = (int*)((float*)tbuf + 200000);       // 100000
    int*   blocksums = (int*)((float*)tbuf + 300000);       // 512

    const int nblk_n = (N_NODES + 255) / 256;   // 391
    const int nblk_e = (N_EDGES + 255) / 256;
    const int nblk_mm = N_NODES / 32;           // 3125
    const int nblk_pool = (N_NODES + POOL_ROWS - 1) / POOL_ROWS;  // 782
    const int nblk_gather = 4096;  // 16384 waves: 2x oversubscription of 8192 slots

    // zero stats/pooled/gcount in one shot (contiguous)
    hipMemsetAsync(stats, 0, (384 + NGRAPH * 64 + NGRAPH) * sizeof(float), stream);

    // ---- degree / dinv / selfnorm + CSR build ----
    k_init<<<nblk_n, 256, 0, stream>>>(dinv, counts);
    k_degcnt<<<nblk_e, 256, 0, stream>>>(dst, (const float2*)edge_attr, dinv, counts);
    k_dinv<<<nblk_n, 256, 0, stream>>>(dinv, selfnorm);
    k_blockreduce<<<NBLK_SCAN, 256, 0, stream>>>(counts, blocksums);
    k_scanblocksums<<<1, 512, 0, stream>>>(blocksums);
    k_blockscan<<<NBLK_SCAN, 256, 0, stream>>>(counts, blocksums, offsets, cursor);
    k_fill<<<nblk_e, 256, 0, stream>>>(src, dst, (const float2*)edge_attr, dinv, cursor, csr);

    // ---- layer 0 (K=8, fp32 in, no affine) ----
    k_matmul<IN_DIM, false, float><<<nblk_mm, 256, 0, stream>>>(
        x, W0, nullptr, nullptr, nullptr, tbuf);
    k_gather<<<nblk_gather, 256, 0, stream>>>(tbuf, offsets, csr, selfnorm, b0, hbuf, stats);

    // ---- layers 1..2 (K=64, bf16 in, BN affine fused into matmul load) ----
    for (int l = 0; l < 2; ++l) {
        k_matmul<DIM, true, bf16_t><<<nblk_mm, 256, 0, stream>>>(
            hbuf, Ws + l * 64 * 64, stats + l * 128, gammas + l * 64, betas + l * 64, tbuf);
        k_gather<<<nblk_gather, 256, 0, stream>>>(tbuf, offsets, csr, selfnorm, bs + l * 64, hbuf,
                                                  stats + (l + 1) * 128);
    }

    // ---- pool (BN affine folded into head via counts) + head ----
    k_pool<<<nblk_pool, 256, 0, stream>>>(batch, hbuf, pooled, gcount);
    k_head<<<NGRAPH, 64, 0, stream>>>(pooled, gcount, stats + 2 * 128,
                                      gammas + 2 * 64, betas + 2 * 64,
                                      lin1_w, lin1_b, lin2_w, lin2_b, out);
}

// Round 5
// 835.006 us; speedup vs baseline: 1.1680x; 1.0202x over previous
//
#include <hip/hip_runtime.h>
#include <math.h>

#define N_NODES 100000
#define N_EDGES 1250000
#define NGRAPH 256
#define IN_DIM 8
#define DIM 64
#define BN_EPS 1e-5f

#define NBLK_SCAN 391  // ceil(100000/256)

typedef unsigned short bf16_t;

static __device__ inline float bf2f(bf16_t u) {
    return __uint_as_float(((unsigned int)u) << 16);
}
static __device__ inline bf16_t f2bf(float f) {
    unsigned int b = __float_as_uint(f);
    b += 0x7fffu + ((b >> 16) & 1u);
    return (bf16_t)(b >> 16);
}

// ---------------- init: deg=1 (self-loop weight), counts=0 ----------------

__global__ void k_init(float* __restrict__ deg, int* __restrict__ counts) {
    int i = blockIdx.x * 256 + threadIdx.x;
    if (i < N_NODES) { deg[i] = 1.0f; counts[i] = 0; }
}

// ---------------- fused degree-sum + in-degree histogram ----------------

__global__ void k_degcnt(const int* __restrict__ dst, const float2* __restrict__ edge_attr,
                         float* __restrict__ deg, int* __restrict__ counts) {
    int e = blockIdx.x * 256 + threadIdx.x;
    if (e < N_EDGES) {
        int d = dst[e];
        atomicAdd(&deg[d], edge_attr[e].y);
        atomicAdd(&counts[d], 1);
    }
}

__global__ void k_dinv(float* __restrict__ deg, float* __restrict__ selfnorm) {
    int i = blockIdx.x * 256 + threadIdx.x;
    if (i < N_NODES) {
        float d = deg[i];
        float r = (d > 0.0f) ? rsqrtf(d) : 0.0f;
        deg[i] = r;
        selfnorm[i] = r * r;
    }
}

// ---------------- CSR build (counting sort by dst) ----------------

__global__ void k_blockreduce(const int* __restrict__ counts, int* __restrict__ blocksums) {
    __shared__ int sh[256];
    int t = threadIdx.x;
    int i = blockIdx.x * 256 + t;
    sh[t] = (i < N_NODES) ? counts[i] : 0;
    __syncthreads();
    for (int off = 128; off > 0; off >>= 1) {
        if (t < off) sh[t] += sh[t + off];
        __syncthreads();
    }
    if (t == 0) blocksums[blockIdx.x] = sh[0];
}

__global__ void k_scanblocksums(int* __restrict__ blocksums) {
    __shared__ int sh[512];
    int t = threadIdx.x;
    int v = (t < NBLK_SCAN) ? blocksums[t] : 0;
    sh[t] = v;
    __syncthreads();
    for (int off = 1; off < 512; off <<= 1) {
        int add = (t >= off) ? sh[t - off] : 0;
        __syncthreads();
        sh[t] += add;
        __syncthreads();
    }
    if (t < NBLK_SCAN) blocksums[t] = sh[t] - v;  // exclusive
}

__global__ void k_blockscan(const int* __restrict__ counts, const int* __restrict__ blocksums,
                            int* __restrict__ offsets, int* __restrict__ cursor) {
    __shared__ int sh[256];
    int t = threadIdx.x;
    int i = blockIdx.x * 256 + t;
    int v = (i < N_NODES) ? counts[i] : 0;
    sh[t] = v;
    __syncthreads();
    for (int off = 1; off < 256; off <<= 1) {
        int add = (t >= off) ? sh[t - off] : 0;
        __syncthreads();
        sh[t] += add;
        __syncthreads();
    }
    int excl = sh[t] - v + blocksums[blockIdx.x];
    if (i < N_NODES) { offsets[i] = excl; cursor[i] = excl; }
    if (i == N_NODES - 1) offsets[N_NODES] = excl + v;  // == E
}

__global__ void k_fill(const int* __restrict__ src, const int* __restrict__ dst,
                       const float2* __restrict__ edge_attr, const float* __restrict__ dinv,
                       int* __restrict__ cursor, int2* __restrict__ csr) {
    int e = blockIdx.x * 256 + threadIdx.x;
    if (e >= N_EDGES) return;
    int s = src[e], d = dst[e];
    float w = edge_attr[e].y;
    int pos = atomicAdd(&cursor[d], 1);
    float nv = dinv[s] * w * dinv[d];
    csr[pos] = make_int2(s, __float_as_int(nv));
}

// ------- matmul: t[N,64] = bn_affine(h)[N,K] @ W[K,64], 32 rows/block, bf16 out -------

template <int K, bool AFFINE, typename TIN>
__global__ void k_matmul(const TIN* __restrict__ h, const float* __restrict__ W,
                         const float* __restrict__ stats, const float* __restrict__ gamma,
                         const float* __restrict__ beta, bf16_t* __restrict__ out) {
    __shared__ float Wsh[K * 64];
    __shared__ float hsh[32 * K];
    __shared__ float scs[K], shs[K];
    int tid = threadIdx.x;
    if (AFFINE) {
        if (tid < K) {
            const float invn = 1.0f / (float)N_NODES;
            float mu = stats[tid] * invn;
            float var = stats[64 + tid] * invn - mu * mu;
            float rs = rsqrtf(var + BN_EPS);
            float sc = gamma[tid] * rs;
            scs[tid] = sc;
            shs[tid] = beta[tid] - sc * mu;
        }
    }
    for (int i = tid; i < K * 64; i += 256) Wsh[i] = W[i];
    __syncthreads();
    int row0 = blockIdx.x * 32;
    if (sizeof(TIN) == 2) {  // bf16 input with affine
        const ushort2* h2 = (const ushort2*)((const bf16_t*)h + row0 * K);
        for (int i = tid; i < 32 * K / 2; i += 256) {
            ushort2 u = h2[i];
            int base = 2 * i;
            int kk = base & (K - 1);
            float sc0 = AFFINE ? scs[kk] : 1.0f, sh0 = AFFINE ? shs[kk] : 0.0f;
            float sc1 = AFFINE ? scs[kk + 1] : 1.0f, sh1 = AFFINE ? shs[kk + 1] : 0.0f;
            hsh[base] = bf2f(u.x) * sc0 + sh0;
            hsh[base + 1] = bf2f(u.y) * sc1 + sh1;
        }
    } else {  // fp32 input, no affine (layer 0)
        const float* hf = (const float*)h + row0 * K;
        for (int i = tid; i < 32 * K; i += 256) hsh[i] = hf[i];
    }
    __syncthreads();
    int c = tid & 63, rs = tid >> 6;  // 64 cols x 4 row-slots, 8 rows each
    float acc[8];
#pragma unroll
    for (int j = 0; j < 8; ++j) acc[j] = 0.0f;
    for (int k = 0; k < K; ++k) {
        float w = Wsh[k * 64 + c];
#pragma unroll
        for (int j = 0; j < 8; ++j) acc[j] += hsh[(rs * 8 + j) * K + k] * w;
    }
#pragma unroll
    for (int j = 0; j < 8; ++j) out[(row0 + rs * 8 + j) * 64 + c] = f2bf(acc[j]);
}

// ------- CSR gather, 8 edges per vmem instruction ----------
// Lane L: edge-slot grp=L>>3 of an 8-edge batch, channel chunk chk=L&7 (8 bf16 = 16B).
// One uint4 load per lane = wave fetches 8 full rows (1 KB) in one vmcnt slot.
// Virtual slot 0 = self-loop; pad slots read t[node] (L1-hot) with weight 0.
// Per-node combine: 3 shfl_xor steps over 8 accumulators. Fused bias+relu+BN-stats.

__global__ void k_gather(const bf16_t* __restrict__ t, const int* __restrict__ offsets,
                         const int2* __restrict__ csr, const float* __restrict__ selfnorm,
                         const float* __restrict__ bias, bf16_t* __restrict__ hout,
                         float* __restrict__ stats) {
    int tid = threadIdx.x;
    int lane = tid & 63;
    int wv = tid >> 6;
    int grp = lane >> 3;  // edge slot within batch
    int chk = lane & 7;   // channel chunk (8 channels)
    float bl[8];
#pragma unroll
    for (int j = 0; j < 8; ++j) bl[j] = bias[chk * 8 + j];
    float ssum[8], ssq[8];
#pragma unroll
    for (int j = 0; j < 8; ++j) { ssum[j] = 0.0f; ssq[j] = 0.0f; }

    int wstride = gridDim.x * 4;
    for (int node = blockIdx.x * 4 + wv; node < N_NODES; node += wstride) {
        int e0 = offsets[node];
        int deg = offsets[node + 1] - e0;
        int nb = (deg + 8) >> 3;  // slots = deg+1 (self)
        float snorm = selfnorm[node];
        float acc[8];
#pragma unroll
        for (int j = 0; j < 8; ++j) acc[j] = 0.0f;

        for (int b = 0; b < nb; b += 2) {
            int nbt = (nb - b < 2) ? (nb - b) : 2;
            int2 pe[2];
            int slot[2];
#pragma unroll
            for (int u = 0; u < 2; ++u) {
                if (u < nbt) {
                    slot[u] = (b + u) * 8 + grp;
                    int idx = e0 + slot[u] - 1;
                    idx = (idx < 0) ? 0 : ((idx >= N_EDGES) ? N_EDGES - 1 : idx);
                    pe[u] = csr[idx];
                }
            }
            uint4 v[2];
            float nv[2];
#pragma unroll
            for (int u = 0; u < 2; ++u) {
                if (u < nbt) {
                    bool isself = (slot[u] == 0);
                    bool isedge = (slot[u] >= 1) && (slot[u] <= deg);
                    int s = isself ? node : (isedge ? pe[u].x : node);
                    nv[u] = isself ? snorm : (isedge ? __int_as_float(pe[u].y) : 0.0f);
                    v[u] = *(const uint4*)(t + s * 64 + chk * 8);
                }
            }
#pragma unroll
            for (int u = 0; u < 2; ++u) {
                if (u < nbt) {
                    float w = nv[u];
                    unsigned int* vp = (unsigned int*)&v[u];
#pragma unroll
                    for (int q = 0; q < 4; ++q) {
                        unsigned int uu = vp[q];
                        float lo = __uint_as_float(uu << 16);
                        float hi = __uint_as_float(uu & 0xffff0000u);
                        acc[2 * q] = fmaf(w, lo, acc[2 * q]);
                        acc[2 * q + 1] = fmaf(w, hi, acc[2 * q + 1]);
                    }
                }
            }
        }
        // reduce across the 8 edge-slot groups (lanes differing in bits 3..5)
#pragma unroll
        for (int j = 0; j < 8; ++j) {
            float a = acc[j];
            a += __shfl_xor(a, 8, 64);
            a += __shfl_xor(a, 16, 64);
            a += __shfl_xor(a, 32, 64);
            acc[j] = a;
        }
        // bias + relu + stats (all groups hold identical values; use group 0 for store)
        unsigned int pk[4];
#pragma unroll
        for (int q = 0; q < 4; ++q) {
            float r0 = fmaxf(acc[2 * q] + bl[2 * q], 0.0f);
            float r1 = fmaxf(acc[2 * q + 1] + bl[2 * q + 1], 0.0f);
            ssum[2 * q] += r0; ssq[2 * q] += r0 * r0;
            ssum[2 * q + 1] += r1; ssq[2 * q + 1] += r1 * r1;
            pk[q] = (unsigned int)f2bf(r0) | ((unsigned int)f2bf(r1) << 16);
        }
        if (grp == 0) {
            *(uint4*)(hout + node * 64 + chk * 8) = make_uint4(pk[0], pk[1], pk[2], pk[3]);
        }
    }
    // block-level BN stats reduction (each channel counted once: use group 0 lanes,
    // whose ssum/ssq hold full per-node values since stats were accumulated
    // post-reduction on all lanes identically)
    __shared__ float s1[4][64], s2[4][64];
    if (grp == 0) {
#pragma unroll
        for (int j = 0; j < 8; ++j) {
            s1[wv][chk * 8 + j] = ssum[j];
            s2[wv][chk * 8 + j] = ssq[j];
        }
    }
    __syncthreads();
    if (tid < 64) {
        atomicAdd(&stats[tid], s1[0][tid] + s1[1][tid] + s1[2][tid] + s1[3][tid]);
        atomicAdd(&stats[64 + tid], s2[0][tid] + s2[1][tid] + s2[2][tid] + s2[3][tid]);
    }
}

// ---------------- pooling over sorted batch (run-length local accumulation) ----------------

#define POOL_ROWS 128

__global__ void k_pool(const int* __restrict__ batch, const bf16_t* __restrict__ h,
                       float* __restrict__ pooled, int* __restrict__ gcount) {
    int c = threadIdx.x & 63;
    int wsub = threadIdx.x >> 6;  // 0..3
    int start = blockIdx.x * POOL_ROWS;
    int end = start + POOL_ROWS; if (end > N_NODES) end = N_NODES;
    int cur = -1, cnt = 0;
    float acc = 0.0f;
    for (int r = start + wsub; r < end; r += 4) {
        int g = batch[r];
        float v = bf2f(h[r * 64 + c]);
        if (g != cur) {
            if (cur >= 0) {
                atomicAdd(&pooled[cur * 64 + c], acc);
                if (c == 0) atomicAdd(&gcount[cur], cnt);
            }
            cur = g; acc = 0.0f; cnt = 0;
        }
        acc += v; cnt += 1;
    }
    if (cur >= 0) {
        atomicAdd(&pooled[cur * 64 + c], acc);
        if (c == 0) atomicAdd(&gcount[cur], cnt);
    }
}

// ------- head: BN affine from raw stats folded via counts, mlp, log_softmax -------

__global__ void k_head(const float* __restrict__ pooled, const int* __restrict__ gcount,
                       const float* __restrict__ stats, const float* __restrict__ gamma,
                       const float* __restrict__ beta, const float* __restrict__ w1,
                       const float* __restrict__ b1, const float* __restrict__ w2,
                       const float* __restrict__ b2, float* __restrict__ out) {
    __shared__ float p[64];
    __shared__ float hid[64];
    __shared__ float o[2];
    int g = blockIdx.x, c = threadIdx.x;
    const float invn = 1.0f / (float)N_NODES;
    float mu = stats[c] * invn;
    float var = stats[64 + c] * invn - mu * mu;
    float rs = rsqrtf(var + BN_EPS);
    float sc = gamma[c] * rs;
    float sh = beta[c] - sc * mu;
    p[c] = sc * pooled[g * 64 + c] + (float)gcount[g] * sh;
    __syncthreads();
    float acc = b1[c];
#pragma unroll
    for (int k = 0; k < 64; ++k) acc += p[k] * w1[k * 64 + c];
    hid[c] = fmaxf(acc, 0.0f);
    __syncthreads();
    if (c < 2) {
        float a = b2[c];
#pragma unroll
        for (int k = 0; k < 64; ++k) a += hid[k] * w2[k * 2 + c];
        o[c] = a;
    }
    __syncthreads();
    if (c == 0) {
        float m = fmaxf(o[0], o[1]);
        float l = m + logf(expf(o[0] - m) + expf(o[1] - m));
        out[g * 2 + 0] = o[0] - l;
        out[g * 2 + 1] = o[1] - l;
    }
}

extern "C" void kernel_launch(void* const* d_in, const int* in_sizes, int n_in,
                              void* d_out, int out_size, void* d_ws, size_t ws_size,
                              hipStream_t stream) {
    const float* x        = (const float*)d_in[0];
    const int*   ei       = (const int*)d_in[1];
    const int*   batch    = (const int*)d_in[2];
    const float* edge_attr= (const float*)d_in[3];
    const float* W0       = (const float*)d_in[4];
    const float* b0       = (const float*)d_in[5];
    const float* Ws       = (const float*)d_in[6];
    const float* bs       = (const float*)d_in[7];
    const float* gammas   = (const float*)d_in[8];
    const float* betas    = (const float*)d_in[9];
    const float* lin1_w   = (const float*)d_in[10];
    const float* lin1_b   = (const float*)d_in[11];
    const float* lin2_w   = (const float*)d_in[12];
    const float* lin2_b   = (const float*)d_in[13];
    float* out = (float*)d_out;

    const int* src = ei;
    const int* dst = ei + N_EDGES;

    // workspace layout (float units, all 16B-aligned where vector-accessed)
    float* ws = (float*)d_ws;
    float*  selfnorm = ws;                                  // 100000
    int*    offsets  = (int*)(ws + 100000);                 // 100001 (pad to 100004)
    int2*   csr      = (int2*)(ws + 200004);                // 2*1250000
    bf16_t* tbuf     = (bf16_t*)(ws + 2700004);             // N*64 bf16 (16B-aligned)
    bf16_t* hbuf     = (bf16_t*)(ws + 5900004);             // N*64 bf16 (16B-aligned)
    float*  stats    = ws + 9100004;                        // 3*128
    float*  pooled   = stats + 384;                         // 16384
    int*    gcount   = (int*)(pooled + NGRAPH * 64);        // 256
    // transient CSR-build aliases inside tbuf (dead before first tbuf write)
    float* dinv      = (float*)tbuf;                        // 100000
    int*   counts    = (int*)((float*)tbuf + 100000);       // 100000
    int*   cursor    = (int*)((float*)tbuf + 200000);       // 100000
    int*   blocksums = (int*)((float*)tbuf + 300000);       // 512

    const int nblk_n = (N_NODES + 255) / 256;   // 391
    const int nblk_e = (N_EDGES + 255) / 256;
    const int nblk_mm = N_NODES / 32;           // 3125
    const int nblk_pool = (N_NODES + POOL_ROWS - 1) / POOL_ROWS;  // 782
    const int nblk_gather = 4096;  // 16384 waves: 2x oversubscription

    // zero stats/pooled/gcount in one shot (contiguous)
    hipMemsetAsync(stats, 0, (384 + NGRAPH * 64 + NGRAPH) * sizeof(float), stream);

    // ---- degree / dinv / selfnorm + CSR build ----
    k_init<<<nblk_n, 256, 0, stream>>>(dinv, counts);
    k_degcnt<<<nblk_e, 256, 0, stream>>>(dst, (const float2*)edge_attr, dinv, counts);
    k_dinv<<<nblk_n, 256, 0, stream>>>(dinv, selfnorm);
    k_blockreduce<<<NBLK_SCAN, 256, 0, stream>>>(counts, blocksums);
    k_scanblocksums<<<1, 512, 0, stream>>>(blocksums);
    k_blockscan<<<NBLK_SCAN, 256, 0, stream>>>(counts, blocksums, offsets, cursor);
    k_fill<<<nblk_e, 256, 0, stream>>>(src, dst, (const float2*)edge_attr, dinv, cursor, csr);

    // ---- layer 0 (K=8, fp32 in, no affine) ----
    k_matmul<IN_DIM, false, float><<<nblk_mm, 256, 0, stream>>>(
        x, W0, nullptr, nullptr, nullptr, tbuf);
    k_gather<<<nblk_gather, 256, 0, stream>>>(tbuf, offsets, csr, selfnorm, b0, hbuf, stats);

    // ---- layers 1..2 (K=64, bf16 in, BN affine fused into matmul load) ----
    for (int l = 0; l < 2; ++l) {
        k_matmul<DIM, true, bf16_t><<<nblk_mm, 256, 0, stream>>>(
            hbuf, Ws + l * 64 * 64, stats + l * 128, gammas + l * 64, betas + l * 64, tbuf);
        k_gather<<<nblk_gather, 256, 0, stream>>>(tbuf, offsets, csr, selfnorm, bs + l * 64, hbuf,
                                                  stats + (l + 1) * 128);
    }

    // ---- pool (BN affine folded into head via counts) + head ----
    k_pool<<<nblk_pool, 256, 0, stream>>>(batch, hbuf, pooled, gcount);
    k_head<<<NGRAPH, 64, 0, stream>>>(pooled, gcount, stats + 2 * 128,
                                      gammas + 2 * 64, betas + 2 * 64,
                                      lin1_w, lin1_b, lin2_w, lin2_b, out);
}

// Round 6
// 729.872 us; speedup vs baseline: 1.3363x; 1.1440x over previous
//
#include <hip/hip_runtime.h>
#include <math.h>

#define N_NODES 100000
#define N_EDGES 1250000
#define NGRAPH 256
#define IN_DIM 8
#define DIM 64
#define BN_EPS 1e-5f

#define NBLK_SCAN 391  // ceil(100000/256)

// ---------------- init: deg=1 (self-loop weight), counts=0 ----------------

__global__ void k_init(float* __restrict__ deg, int* __restrict__ counts) {
    int i = blockIdx.x * 256 + threadIdx.x;
    if (i < N_NODES) { deg[i] = 1.0f; counts[i] = 0; }
}

// ---------------- fused degree-sum + in-degree histogram ----------------

__global__ void k_degcnt(const int* __restrict__ dst, const float2* __restrict__ edge_attr,
                         float* __restrict__ deg, int* __restrict__ counts) {
    int e = blockIdx.x * 256 + threadIdx.x;
    if (e < N_EDGES) {
        int d = dst[e];
        atomicAdd(&deg[d], edge_attr[e].y);
        atomicAdd(&counts[d], 1);
    }
}

// dinv + selfnorm + dvec init (dvec starts at selfnorm, k_fill adds edge norms)

__global__ void k_dinv(float* __restrict__ deg, float* __restrict__ selfnorm,
                       float* __restrict__ dvec) {
    int i = blockIdx.x * 256 + threadIdx.x;
    if (i < N_NODES) {
        float d = deg[i];
        float r = (d > 0.0f) ? rsqrtf(d) : 0.0f;
        deg[i] = r;
        selfnorm[i] = r * r;
        dvec[i] = r * r;
    }
}

// ---------------- CSR build (counting sort by dst) ----------------

__global__ void k_blockreduce(const int* __restrict__ counts, int* __restrict__ blocksums) {
    __shared__ int sh[256];
    int t = threadIdx.x;
    int i = blockIdx.x * 256 + t;
    sh[t] = (i < N_NODES) ? counts[i] : 0;
    __syncthreads();
    for (int off = 128; off > 0; off >>= 1) {
        if (t < off) sh[t] += sh[t + off];
        __syncthreads();
    }
    if (t == 0) blocksums[blockIdx.x] = sh[0];
}

__global__ void k_scanblocksums(int* __restrict__ blocksums) {
    __shared__ int sh[512];
    int t = threadIdx.x;
    int v = (t < NBLK_SCAN) ? blocksums[t] : 0;
    sh[t] = v;
    __syncthreads();
    for (int off = 1; off < 512; off <<= 1) {
        int add = (t >= off) ? sh[t - off] : 0;
        __syncthreads();
        sh[t] += add;
        __syncthreads();
    }
    if (t < NBLK_SCAN) blocksums[t] = sh[t] - v;  // exclusive
}

__global__ void k_blockscan(const int* __restrict__ counts, const int* __restrict__ blocksums,
                            int* __restrict__ offsets, int* __restrict__ cursor) {
    __shared__ int sh[256];
    int t = threadIdx.x;
    int i = blockIdx.x * 256 + t;
    int v = (i < N_NODES) ? counts[i] : 0;
    sh[t] = v;
    __syncthreads();
    for (int off = 1; off < 256; off <<= 1) {
        int add = (t >= off) ? sh[t - off] : 0;
        __syncthreads();
        sh[t] += add;
        __syncthreads();
    }
    int excl = sh[t] - v + blocksums[blockIdx.x];
    if (i < N_NODES) { offsets[i] = excl; cursor[i] = excl; }
    if (i == N_NODES - 1) offsets[N_NODES] = excl + v;  // == E
}

__global__ void k_fill(const int* __restrict__ src, const int* __restrict__ dst,
                       const float2* __restrict__ edge_attr, const float* __restrict__ dinv,
                       int* __restrict__ cursor, int2* __restrict__ csr,
                       float* __restrict__ dvec) {
    int e = blockIdx.x * 256 + threadIdx.x;
    if (e >= N_EDGES) return;
    int s = src[e], d = dst[e];
    float w = edge_attr[e].y;
    int pos = atomicAdd(&cursor[d], 1);
    float nv = dinv[s] * w * dinv[d];
    csr[pos] = make_int2(s, __float_as_int(nv));
    atomicAdd(&dvec[d], nv);  // row-sum of A-hat (for BN shift folding)
}

// ------- raw aggregation, 8-channel (layer 0 input x): AGG = A-hat @ x -------
// thread = (node, ch): 8 threads share a node; per edge, 8 lanes read 32B row.

__global__ void k_agg8(const float* __restrict__ x, const int* __restrict__ offsets,
                       const int2* __restrict__ csr, const float* __restrict__ selfnorm,
                       float* __restrict__ agg) {
    int t = blockIdx.x * 256 + threadIdx.x;  // N*8 threads
    int node = t >> 3, ch = t & 7;
    float acc = selfnorm[node] * x[node * 8 + ch];
    int e0 = offsets[node], e1 = offsets[node + 1];
    for (int e = e0; e < e1; ++e) {
        int2 p = csr[e];
        acc = fmaf(__int_as_float(p.y), x[p.x * 8 + ch], acc);
    }
    agg[t] = acc;
}

// ------- raw aggregation, 64-channel: AGG = A-hat @ r  (proven R2 shape) -------
// one wave per node, lane = channel, serial edge loop, fully coalesced 256B rows.

__global__ void k_gather64(const float* __restrict__ t, const int* __restrict__ offsets,
                           const int2* __restrict__ csr, const float* __restrict__ selfnorm,
                           float* __restrict__ agg) {
    int wid = (blockIdx.x * 256 + threadIdx.x) >> 6;
    int lane = threadIdx.x & 63;
    if (wid >= N_NODES) return;
    float acc = selfnorm[wid] * t[wid * 64 + lane];
    int e0 = offsets[wid], e1 = offsets[wid + 1];
    for (int e = e0; e < e1; ++e) {
        int2 p = csr[e];
        acc = fmaf(__int_as_float(p.y), t[p.x * 64 + lane], acc);
    }
    agg[wid * 64 + lane] = acc;
}

// ------- fused layer matmul -------
// r_out = relu( (AFFINE ? AGG*sc + dvec*sh : AGG) @ W + bias ), plus BN stats of
// r_out accumulated into 8 bins (statsout[bin*128 + c], [bin*128+64+c]).

template <int K, bool AFFINE>
__global__ void k_mm(const float* __restrict__ agg, const float* __restrict__ dvec,
                     const float* __restrict__ statsin, const float* __restrict__ gamma,
                     const float* __restrict__ beta, const float* __restrict__ W,
                     const float* __restrict__ bias, float* __restrict__ rout,
                     float* __restrict__ statsout) {
    __shared__ float Wsh[K * 64];
    __shared__ float hsh[32 * K];
    __shared__ float scs[K], shs[K];
    int tid = threadIdx.x;
    if (AFFINE && tid < K) {
        float s = 0.0f, q = 0.0f;
#pragma unroll
        for (int b = 0; b < 8; ++b) {
            s += statsin[b * 128 + tid];
            q += statsin[b * 128 + 64 + tid];
        }
        const float invn = 1.0f / (float)N_NODES;
        float mu = s * invn;
        float var = q * invn - mu * mu;
        float rs = rsqrtf(var + BN_EPS);
        float sc = gamma[tid] * rs;
        scs[tid] = sc;
        shs[tid] = beta[tid] - sc * mu;
    }
    for (int i = tid; i < K * 64; i += 256) Wsh[i] = W[i];
    __syncthreads();
    int row0 = blockIdx.x * 32;
    if (AFFINE) {
        for (int i = tid; i < 32 * K; i += 256) {
            int rr = i / K, kk = i - rr * K;
            hsh[i] = agg[row0 * K + i] * scs[kk] + dvec[row0 + rr] * shs[kk];
        }
    } else {
        for (int i = tid; i < 32 * K; i += 256) hsh[i] = agg[row0 * K + i];
    }
    __syncthreads();
    int c = tid & 63, rsl = tid >> 6;  // 64 cols x 4 row-slots, 8 rows each
    float b_c = bias[c];
    float acc[8];
#pragma unroll
    for (int j = 0; j < 8; ++j) acc[j] = 0.0f;
    for (int k = 0; k < K; ++k) {
        float w = Wsh[k * 64 + c];
#pragma unroll
        for (int j = 0; j < 8; ++j) acc[j] += hsh[(rsl * 8 + j) * K + k] * w;
    }
    float sum = 0.0f, ssq = 0.0f;
#pragma unroll
    for (int j = 0; j < 8; ++j) {
        float v = fmaxf(acc[j] + b_c, 0.0f);
        rout[(row0 + rsl * 8 + j) * 64 + c] = v;
        sum += v;
        ssq += v * v;
    }
    __shared__ float s1[256], s2[256];
    s1[tid] = sum; s2[tid] = ssq;
    __syncthreads();
    if (tid < 64) {
        int bin = blockIdx.x & 7;
        atomicAdd(&statsout[bin * 128 + tid],
                  s1[tid] + s1[tid + 64] + s1[tid + 128] + s1[tid + 192]);
        atomicAdd(&statsout[bin * 128 + 64 + tid],
                  s2[tid] + s2[tid + 64] + s2[tid + 128] + s2[tid + 192]);
    }
}

// ---------------- pooling over sorted batch (run-length local accumulation) ----------------

#define POOL_ROWS 128

__global__ void k_pool(const int* __restrict__ batch, const float* __restrict__ h,
                       float* __restrict__ pooled, int* __restrict__ gcount) {
    int c = threadIdx.x & 63;
    int wsub = threadIdx.x >> 6;  // 0..3
    int start = blockIdx.x * POOL_ROWS;
    int end = start + POOL_ROWS; if (end > N_NODES) end = N_NODES;
    int cur = -1, cnt = 0;
    float acc = 0.0f;
    for (int r = start + wsub; r < end; r += 4) {
        int g = batch[r];
        float v = h[r * 64 + c];
        if (g != cur) {
            if (cur >= 0) {
                atomicAdd(&pooled[cur * 64 + c], acc);
                if (c == 0) atomicAdd(&gcount[cur], cnt);
            }
            cur = g; acc = 0.0f; cnt = 0;
        }
        acc += v; cnt += 1;
    }
    if (cur >= 0) {
        atomicAdd(&pooled[cur * 64 + c], acc);
        if (c == 0) atomicAdd(&gcount[cur], cnt);
    }
}

// ------- head: BN affine from binned stats folded via counts, mlp, log_softmax -------

__global__ void k_head(const float* __restrict__ pooled, const int* __restrict__ gcount,
                       const float* __restrict__ stats, const float* __restrict__ gamma,
                       const float* __restrict__ beta, const float* __restrict__ w1,
                       const float* __restrict__ b1, const float* __restrict__ w2,
                       const float* __restrict__ b2, float* __restrict__ out) {
    __shared__ float p[64];
    __shared__ float hid[64];
    __shared__ float o[2];
    int g = blockIdx.x, c = threadIdx.x;
    float s = 0.0f, q = 0.0f;
#pragma unroll
    for (int b = 0; b < 8; ++b) {
        s += stats[b * 128 + c];
        q += stats[b * 128 + 64 + c];
    }
    const float invn = 1.0f / (float)N_NODES;
    float mu = s * invn;
    float var = q * invn - mu * mu;
    float rs = rsqrtf(var + BN_EPS);
    float sc = gamma[c] * rs;
    float sh = beta[c] - sc * mu;
    p[c] = sc * pooled[g * 64 + c] + (float)gcount[g] * sh;
    __syncthreads();
    float acc = b1[c];
#pragma unroll
    for (int k = 0; k < 64; ++k) acc += p[k] * w1[k * 64 + c];
    hid[c] = fmaxf(acc, 0.0f);
    __syncthreads();
    if (c < 2) {
        float a = b2[c];
#pragma unroll
        for (int k = 0; k < 64; ++k) a += hid[k] * w2[k * 2 + c];
        o[c] = a;
    }
    __syncthreads();
    if (c == 0) {
        float m = fmaxf(o[0], o[1]);
        float l = m + logf(expf(o[0] - m) + expf(o[1] - m));
        out[g * 2 + 0] = o[0] - l;
        out[g * 2 + 1] = o[1] - l;
    }
}

extern "C" void kernel_launch(void* const* d_in, const int* in_sizes, int n_in,
                              void* d_out, int out_size, void* d_ws, size_t ws_size,
                              hipStream_t stream) {
    const float* x        = (const float*)d_in[0];
    const int*   ei       = (const int*)d_in[1];
    const int*   batch    = (const int*)d_in[2];
    const float* edge_attr= (const float*)d_in[3];
    const float* W0       = (const float*)d_in[4];
    const float* b0       = (const float*)d_in[5];
    const float* Ws       = (const float*)d_in[6];
    const float* bs       = (const float*)d_in[7];
    const float* gammas   = (const float*)d_in[8];
    const float* betas    = (const float*)d_in[9];
    const float* lin1_w   = (const float*)d_in[10];
    const float* lin1_b   = (const float*)d_in[11];
    const float* lin2_w   = (const float*)d_in[12];
    const float* lin2_b   = (const float*)d_in[13];
    float* out = (float*)d_out;

    const int* src = ei;
    const int* dst = ei + N_EDGES;

    // workspace layout (float units)
    float* ws = (float*)d_ws;
    float* selfnorm = ws;                       // [0, 100000)
    float* dvec     = ws + 100000;              // [100000, 200000)
    int*   offsets  = (int*)(ws + 200000);      // 100001 ints, pad to 100004
    int2*  csr      = (int2*)(ws + 300004);     // 2.5M floats
    float* bufA     = ws + 2800004;             // N*64 (r buffers)
    float* bufB     = bufA + (size_t)N_NODES * 64;  // N*64 (AGG buffers)
    float* stats    = bufB + (size_t)N_NODES * 64;  // 3 layers * 8 bins * 128
    float* pooled   = stats + 3 * 1024;         // 16384
    int*   gcount   = (int*)(pooled + NGRAPH * 64);  // 256
    // transient CSR-build aliases inside bufA (dead before mm0 writes bufA)
    float* dinv      = bufA;                    // 100000
    int*   counts    = (int*)(bufA + 100000);   // 100000
    int*   cursor    = (int*)(bufA + 200000);   // 100000
    int*   blocksums = (int*)(bufA + 300000);   // 512

    const int nblk_n = (N_NODES + 255) / 256;       // 391
    const int nblk_e = (N_EDGES + 255) / 256;       // 4883
    const int nblk_a8 = N_NODES * 8 / 256;          // 3125
    const int nblk_g64 = N_NODES * 64 / 256;        // 25000
    const int nblk_mm = N_NODES / 32;               // 3125
    const int nblk_pool = (N_NODES + POOL_ROWS - 1) / POOL_ROWS;  // 782

    // zero stats + pooled + gcount in one contiguous memset
    hipMemsetAsync(stats, 0, (3 * 1024 + NGRAPH * 64 + NGRAPH) * sizeof(float), stream);

    // ---- degree / dinv / selfnorm / dvec + CSR build ----
    k_init<<<nblk_n, 256, 0, stream>>>(dinv, counts);
    k_degcnt<<<nblk_e, 256, 0, stream>>>(dst, (const float2*)edge_attr, dinv, counts);
    k_dinv<<<nblk_n, 256, 0, stream>>>(dinv, selfnorm, dvec);
    k_blockreduce<<<NBLK_SCAN, 256, 0, stream>>>(counts, blocksums);
    k_scanblocksums<<<1, 512, 0, stream>>>(blocksums);
    k_blockscan<<<NBLK_SCAN, 256, 0, stream>>>(counts, blocksums, offsets, cursor);
    k_fill<<<nblk_e, 256, 0, stream>>>(src, dst, (const float2*)edge_attr, dinv,
                                       cursor, csr, dvec);

    // ---- layer 0: AGG0 = A-hat @ x (8ch), r0 = relu(AGG0 @ W0 + b0) + stats ----
    k_agg8<<<nblk_a8, 256, 0, stream>>>(x, offsets, csr, selfnorm, bufB);
    k_mm<IN_DIM, false><<<nblk_mm, 256, 0, stream>>>(
        bufB, nullptr, nullptr, nullptr, nullptr, W0, b0, bufA, stats);

    // ---- layers 1..2: AGG = A-hat @ r, r' = relu((AGG*sc + dvec*sh) @ W + b) + stats ----
    for (int l = 0; l < 2; ++l) {
        k_gather64<<<nblk_g64, 256, 0, stream>>>(bufA, offsets, csr, selfnorm, bufB);
        k_mm<DIM, true><<<nblk_mm, 256, 0, stream>>>(
            bufB, dvec, stats + l * 1024, gammas + l * 64, betas + l * 64,
            Ws + l * 64 * 64, bs + l * 64, bufA, stats + (l + 1) * 1024);
    }

    // ---- pool raw r2 (BN affine folded into head via counts) + head ----
    k_pool<<<nblk_pool, 256, 0, stream>>>(batch, bufA, pooled, gcount);
    k_head<<<NGRAPH, 64, 0, stream>>>(pooled, gcount, stats + 2 * 1024,
                                      gammas + 2 * 64, betas + 2 * 64,
                                      lin1_w, lin1_b, lin2_w, lin2_b, out);
}

// Round 7
// 694.298 us; speedup vs baseline: 1.4048x; 1.0512x over previous
//
#include <hip/hip_runtime.h>
#include <math.h>

#define N_NODES 100000
#define N_EDGES 1250000
#define NGRAPH 256
#define IN_DIM 8
#define DIM 64
#define BN_EPS 1e-5f

#define NBLK_SCAN 391  // ceil(100000/256)

typedef unsigned short bf16_t;

static __device__ inline float bf2f(bf16_t u) {
    return __uint_as_float(((unsigned int)u) << 16);
}
static __device__ inline bf16_t f2bf(float f) {
    unsigned int b = __float_as_uint(f);
    b += 0x7fffu + ((b >> 16) & 1u);
    return (bf16_t)(b >> 16);
}

// ---------------- fused degree-sum + in-degree histogram (deg starts at 0) ----------------

__global__ void k_degcnt(const int* __restrict__ dst, const float2* __restrict__ edge_attr,
                         float* __restrict__ deg, int* __restrict__ counts) {
    int e = blockIdx.x * 256 + threadIdx.x;
    if (e < N_EDGES) {
        int d = dst[e];
        atomicAdd(&deg[d], edge_attr[e].y);
        atomicAdd(&counts[d], 1);
    }
}

// dinv + selfnorm (self-loop weight 1 folded in here: deg_total = deg + 1 > 0 always)

__global__ void k_dinv(float* __restrict__ deg, float* __restrict__ selfnorm) {
    int i = blockIdx.x * 256 + threadIdx.x;
    if (i < N_NODES) {
        float r = rsqrtf(deg[i] + 1.0f);
        deg[i] = r;
        selfnorm[i] = r * r;
    }
}

// ---------------- CSR build (counting sort by dst) ----------------

__global__ void k_blockreduce(const int* __restrict__ counts, int* __restrict__ blocksums) {
    __shared__ int sh[256];
    int t = threadIdx.x;
    int i = blockIdx.x * 256 + t;
    sh[t] = (i < N_NODES) ? counts[i] : 0;
    __syncthreads();
    for (int off = 128; off > 0; off >>= 1) {
        if (t < off) sh[t] += sh[t + off];
        __syncthreads();
    }
    if (t == 0) blocksums[blockIdx.x] = sh[0];
}

__global__ void k_scanblocksums(int* __restrict__ blocksums) {
    __shared__ int sh[512];
    int t = threadIdx.x;
    int v = (t < NBLK_SCAN) ? blocksums[t] : 0;
    sh[t] = v;
    __syncthreads();
    for (int off = 1; off < 512; off <<= 1) {
        int add = (t >= off) ? sh[t - off] : 0;
        __syncthreads();
        sh[t] += add;
        __syncthreads();
    }
    if (t < NBLK_SCAN) blocksums[t] = sh[t] - v;  // exclusive
}

__global__ void k_blockscan(const int* __restrict__ counts, const int* __restrict__ blocksums,
                            int* __restrict__ offsets, int* __restrict__ cursor) {
    __shared__ int sh[256];
    int t = threadIdx.x;
    int i = blockIdx.x * 256 + t;
    int v = (i < N_NODES) ? counts[i] : 0;
    sh[t] = v;
    __syncthreads();
    for (int off = 1; off < 256; off <<= 1) {
        int add = (t >= off) ? sh[t - off] : 0;
        __syncthreads();
        sh[t] += add;
        __syncthreads();
    }
    int excl = sh[t] - v + blocksums[blockIdx.x];
    if (i < N_NODES) { offsets[i] = excl; cursor[i] = excl; }
    if (i == N_NODES - 1) offsets[N_NODES] = excl + v;  // == E
}

__global__ void k_fill(const int* __restrict__ src, const int* __restrict__ dst,
                       const float2* __restrict__ edge_attr, const float* __restrict__ dinv,
                       int* __restrict__ cursor, int2* __restrict__ csr) {
    int e = blockIdx.x * 256 + threadIdx.x;
    if (e >= N_EDGES) return;
    int s = src[e], d = dst[e];
    float w = edge_attr[e].y;
    int pos = atomicAdd(&cursor[d], 1);
    float nv = dinv[s] * w * dinv[d];
    csr[pos] = make_int2(s, __float_as_int(nv));
}

// ------- fused layer 0: agg (8ch, random 32B rows) + matmul 8x64 + relu + stats -------
// block = 32 nodes x 8 lanes. Lane ch aggregates channel ch, then computes output
// columns ch*8..ch*8+7 via intra-group shfl broadcast of the 8 agg values.

__global__ void k_aggmm0(const float* __restrict__ x, const int* __restrict__ offsets,
                         const int2* __restrict__ csr, const float* __restrict__ selfnorm,
                         const float* __restrict__ W0, const float* __restrict__ b0,
                         bf16_t* __restrict__ rout, float* __restrict__ stats) {
    __shared__ float Wsh[IN_DIM * 64];
    __shared__ float bsh[64];
    __shared__ float sstat[64], sq[64];
    int tid = threadIdx.x;
    for (int i = tid; i < IN_DIM * 64; i += 256) Wsh[i] = W0[i];
    if (tid < 64) { bsh[tid] = b0[tid]; sstat[tid] = 0.0f; sq[tid] = 0.0f; }
    __syncthreads();
    int node = blockIdx.x * 32 + (tid >> 3);
    int ch = tid & 7;
    float acc = selfnorm[node] * x[node * 8 + ch];
    int e0 = offsets[node], e1 = offsets[node + 1];
    for (int e = e0; e < e1; ++e) {
        int2 p = csr[e];
        acc = fmaf(__int_as_float(p.y), x[p.x * 8 + ch], acc);
    }
    float a[8];
#pragma unroll
    for (int k = 0; k < 8; ++k) a[k] = __shfl(acc, k, 8);
    unsigned int pk[4];
#pragma unroll
    for (int q = 0; q < 4; ++q) {
        float v0, v1;
#pragma unroll
        for (int h = 0; h < 2; ++h) {
            int c = ch * 8 + 2 * q + h;
            float v = bsh[c];
#pragma unroll
            for (int k = 0; k < 8; ++k) v = fmaf(a[k], Wsh[k * 64 + c], v);
            v = fmaxf(v, 0.0f);
            atomicAdd(&sstat[c], v);
            atomicAdd(&sq[c], v * v);
            if (h == 0) v0 = v; else v1 = v;
        }
        pk[q] = (unsigned int)f2bf(v0) | ((unsigned int)f2bf(v1) << 16);
    }
    *(uint4*)(rout + node * 64 + ch * 8) = make_uint4(pk[0], pk[1], pk[2], pk[3]);
    __syncthreads();
    if (tid < 64) {
        int bin = blockIdx.x & 7;
        atomicAdd(&stats[bin * 128 + tid], sstat[tid]);
        atomicAdd(&stats[bin * 128 + 64 + tid], sq[tid]);
    }
}

// ------- raw aggregation, 64-channel bf16 table (R2-proven shape) -------
// one wave per node, lane = channel, serial edge loop, 128B coalesced rows.
// #1 also emits dvec = A-hat row-sum (selfnorm + sum nv) for BN-shift folding.

__global__ void k_gather64(const bf16_t* __restrict__ t, const int* __restrict__ offsets,
                           const int2* __restrict__ csr, const float* __restrict__ selfnorm,
                           float* __restrict__ agg, float* __restrict__ dvec) {
    int wid = (blockIdx.x * 256 + threadIdx.x) >> 6;
    int lane = threadIdx.x & 63;
    if (wid >= N_NODES) return;
    float sn = selfnorm[wid];
    float acc = sn * bf2f(t[wid * 64 + lane]);
    float nvs = sn;
    int e0 = offsets[wid], e1 = offsets[wid + 1];
    for (int e = e0; e < e1; ++e) {
        int2 p = csr[e];
        float nv = __int_as_float(p.y);
        acc = fmaf(nv, bf2f(t[p.x * 64 + lane]), acc);
        nvs += nv;
    }
    agg[wid * 64 + lane] = acc;
    if (dvec != nullptr && lane == 0) dvec[wid] = nvs;
}

// ------- mid layer matmul: r' = relu((AGG*sc + dvec*sh) @ W + b), bf16 out, stats -------

__global__ void k_mm1(const float* __restrict__ agg, const float* __restrict__ dvec,
                      const float* __restrict__ statsin, const float* __restrict__ gamma,
                      const float* __restrict__ beta, const float* __restrict__ W,
                      const float* __restrict__ bias, bf16_t* __restrict__ rout,
                      float* __restrict__ statsout) {
    __shared__ float Wsh[64 * 64];
    __shared__ float hsh[32 * 64];
    __shared__ float scs[64], shs[64];
    __shared__ float s1[256], s2[256];
    int tid = threadIdx.x;
    if (tid < 64) {
        float s = 0.0f, q = 0.0f;
#pragma unroll
        for (int b = 0; b < 8; ++b) {
            s += statsin[b * 128 + tid];
            q += statsin[b * 128 + 64 + tid];
        }
        const float invn = 1.0f / (float)N_NODES;
        float mu = s * invn;
        float var = q * invn - mu * mu;
        float rs = rsqrtf(var + BN_EPS);
        float sc = gamma[tid] * rs;
        scs[tid] = sc;
        shs[tid] = beta[tid] - sc * mu;
    }
    for (int i = tid; i < 64 * 64; i += 256) Wsh[i] = W[i];
    __syncthreads();
    int row0 = blockIdx.x * 32;
    for (int i = tid; i < 32 * 64; i += 256) {
        int rr = i >> 6, kk = i & 63;
        hsh[i] = agg[row0 * 64 + i] * scs[kk] + dvec[row0 + rr] * shs[kk];
    }
    __syncthreads();
    int c = tid & 63, rsl = tid >> 6;
    float b_c = bias[c];
    float acc[8];
#pragma unroll
    for (int j = 0; j < 8; ++j) acc[j] = 0.0f;
    for (int k = 0; k < 64; ++k) {
        float w = Wsh[k * 64 + c];
#pragma unroll
        for (int j = 0; j < 8; ++j) acc[j] += hsh[(rsl * 8 + j) * 64 + k] * w;
    }
    float sum = 0.0f, ssq = 0.0f;
#pragma unroll
    for (int j = 0; j < 8; ++j) {
        float v = fmaxf(acc[j] + b_c, 0.0f);
        rout[(row0 + rsl * 8 + j) * 64 + c] = f2bf(v);
        sum += v;
        ssq += v * v;
    }
    s1[tid] = sum; s2[tid] = ssq;
    __syncthreads();
    if (tid < 64) {
        int bin = blockIdx.x & 7;
        atomicAdd(&statsout[bin * 128 + tid],
                  s1[tid] + s1[tid + 64] + s1[tid + 128] + s1[tid + 192]);
        atomicAdd(&statsout[bin * 128 + 64 + tid],
                  s2[tid] + s2[tid + 64] + s2[tid + 128] + s2[tid + 192]);
    }
}

// ------- final layer matmul + fused pooling: r2 never touches global memory -------

__global__ void k_mm2(const float* __restrict__ agg, const float* __restrict__ dvec,
                      const float* __restrict__ statsin, const float* __restrict__ gamma,
                      const float* __restrict__ beta, const float* __restrict__ W,
                      const float* __restrict__ bias, const int* __restrict__ batch,
                      float* __restrict__ pooled, int* __restrict__ gcount,
                      float* __restrict__ statsout) {
    __shared__ float Wsh[64 * 64];
    __shared__ float hsh[32 * 64];
    __shared__ float rt[32 * 64];
    __shared__ float scs[64], shs[64];
    __shared__ float s1[256], s2[256];
    __shared__ int sbatch[32];
    int tid = threadIdx.x;
    int row0 = blockIdx.x * 32;
    if (tid < 64) {
        float s = 0.0f, q = 0.0f;
#pragma unroll
        for (int b = 0; b < 8; ++b) {
            s += statsin[b * 128 + tid];
            q += statsin[b * 128 + 64 + tid];
        }
        const float invn = 1.0f / (float)N_NODES;
        float mu = s * invn;
        float var = q * invn - mu * mu;
        float rs = rsqrtf(var + BN_EPS);
        float sc = gamma[tid] * rs;
        scs[tid] = sc;
        shs[tid] = beta[tid] - sc * mu;
    }
    if (tid >= 64 && tid < 96) sbatch[tid - 64] = batch[row0 + tid - 64];
    for (int i = tid; i < 64 * 64; i += 256) Wsh[i] = W[i];
    __syncthreads();
    for (int i = tid; i < 32 * 64; i += 256) {
        int rr = i >> 6, kk = i & 63;
        hsh[i] = agg[row0 * 64 + i] * scs[kk] + dvec[row0 + rr] * shs[kk];
    }
    __syncthreads();
    int c = tid & 63, rsl = tid >> 6;
    float b_c = bias[c];
    float acc[8];
#pragma unroll
    for (int j = 0; j < 8; ++j) acc[j] = 0.0f;
    for (int k = 0; k < 64; ++k) {
        float w = Wsh[k * 64 + c];
#pragma unroll
        for (int j = 0; j < 8; ++j) acc[j] += hsh[(rsl * 8 + j) * 64 + k] * w;
    }
    float sum = 0.0f, ssq = 0.0f;
#pragma unroll
    for (int j = 0; j < 8; ++j) {
        float v = fmaxf(acc[j] + b_c, 0.0f);
        rt[(rsl * 8 + j) * 64 + c] = v;
        sum += v;
        ssq += v * v;
    }
    s1[tid] = sum; s2[tid] = ssq;
    __syncthreads();
    if (tid < 64) {
        // run-length pooling over 32 sorted rows
        int cur = sbatch[0], cnt = 0;
        float a = 0.0f;
        for (int r = 0; r < 32; ++r) {
            int g = sbatch[r];
            if (g != cur) {
                atomicAdd(&pooled[cur * 64 + c], a);
                if (c == 0) atomicAdd(&gcount[cur], cnt);
                cur = g; a = 0.0f; cnt = 0;
            }
            a += rt[r * 64 + c];
            cnt += 1;
        }
        atomicAdd(&pooled[cur * 64 + c], a);
        if (c == 0) atomicAdd(&gcount[cur], cnt);
        int bin = blockIdx.x & 7;
        atomicAdd(&statsout[bin * 128 + tid],
                  s1[tid] + s1[tid + 64] + s1[tid + 128] + s1[tid + 192]);
        atomicAdd(&statsout[bin * 128 + 64 + tid],
                  s2[tid] + s2[tid + 64] + s2[tid + 128] + s2[tid + 192]);
    }
}

// ------- head: BN affine from binned stats folded via counts, mlp, log_softmax -------

__global__ void k_head(const float* __restrict__ pooled, const int* __restrict__ gcount,
                       const float* __restrict__ stats, const float* __restrict__ gamma,
                       const float* __restrict__ beta, const float* __restrict__ w1,
                       const float* __restrict__ b1, const float* __restrict__ w2,
                       const float* __restrict__ b2, float* __restrict__ out) {
    __shared__ float p[64];
    __shared__ float hid[64];
    __shared__ float o[2];
    int g = blockIdx.x, c = threadIdx.x;
    float s = 0.0f, q = 0.0f;
#pragma unroll
    for (int b = 0; b < 8; ++b) {
        s += stats[b * 128 + c];
        q += stats[b * 128 + 64 + c];
    }
    const float invn = 1.0f / (float)N_NODES;
    float mu = s * invn;
    float var = q * invn - mu * mu;
    float rs = rsqrtf(var + BN_EPS);
    float sc = gamma[c] * rs;
    float sh = beta[c] - sc * mu;
    p[c] = sc * pooled[g * 64 + c] + (float)gcount[g] * sh;
    __syncthreads();
    float acc = b1[c];
#pragma unroll
    for (int k = 0; k < 64; ++k) acc += p[k] * w1[k * 64 + c];
    hid[c] = fmaxf(acc, 0.0f);
    __syncthreads();
    if (c < 2) {
        float a = b2[c];
#pragma unroll
        for (int k = 0; k < 64; ++k) a += hid[k] * w2[k * 2 + c];
        o[c] = a;
    }
    __syncthreads();
    if (c == 0) {
        float m = fmaxf(o[0], o[1]);
        float l = m + logf(expf(o[0] - m) + expf(o[1] - m));
        out[g * 2 + 0] = o[0] - l;
        out[g * 2 + 1] = o[1] - l;
    }
}

extern "C" void kernel_launch(void* const* d_in, const int* in_sizes, int n_in,
                              void* d_out, int out_size, void* d_ws, size_t ws_size,
                              hipStream_t stream) {
    const float* x        = (const float*)d_in[0];
    const int*   ei       = (const int*)d_in[1];
    const int*   batch    = (const int*)d_in[2];
    const float* edge_attr= (const float*)d_in[3];
    const float* W0       = (const float*)d_in[4];
    const float* b0       = (const float*)d_in[5];
    const float* Ws       = (const float*)d_in[6];
    const float* bs       = (const float*)d_in[7];
    const float* gammas   = (const float*)d_in[8];
    const float* betas    = (const float*)d_in[9];
    const float* lin1_w   = (const float*)d_in[10];
    const float* lin1_b   = (const float*)d_in[11];
    const float* lin2_w   = (const float*)d_in[12];
    const float* lin2_b   = (const float*)d_in[13];
    float* out = (float*)d_out;

    const int* src = ei;
    const int* dst = ei + N_EDGES;

    // workspace layout (float units)
    float*  ws0      = (float*)d_ws;
    float*  selfnorm = ws0;                             // 100000
    int*    offsets  = (int*)(ws0 + 100000);            // 100001, pad to 100004
    float*  dvec     = ws0 + 200004;                    // 100000
    int2*   csr      = (int2*)(ws0 + 300004);           // 2.5M floats
    bf16_t* rbuf     = (bf16_t*)(ws0 + 2800004);        // N*64 bf16 = 3.2M floats
    float*  aggbuf   = ws0 + 6000004;                   // N*64 fp32 = 6.4M floats
    float*  stats    = aggbuf + (size_t)N_NODES * 64;   // 3*1024
    float*  pooled   = stats + 3 * 1024;                // 16384
    int*    gcount   = (int*)(pooled + NGRAPH * 64);    // 256
    // transient CSR-build aliases inside aggbuf (dead before gather#1 writes it)
    float* deg       = aggbuf;                          // 100000
    int*   counts    = (int*)(aggbuf + 100000);         // 100000 (adjacent to deg)
    int*   cursor    = (int*)(aggbuf + 200000);         // 100000
    int*   blocksums = (int*)(aggbuf + 300000);         // 512

    const int nblk_n = (N_NODES + 255) / 256;        // 391
    const int nblk_e = (N_EDGES + 255) / 256;        // 4883
    const int nblk_g64 = N_NODES * 64 / 256;         // 25000
    const int nblk_mm = N_NODES / 32;                // 3125

    // zero deg+counts (adjacent) and stats+pooled+gcount (adjacent)
    hipMemsetAsync(deg, 0, 200000 * sizeof(float), stream);
    hipMemsetAsync(stats, 0, (3 * 1024 + NGRAPH * 64 + NGRAPH) * sizeof(float), stream);

    // ---- degree / dinv / selfnorm + CSR build ----
    k_degcnt<<<nblk_e, 256, 0, stream>>>(dst, (const float2*)edge_attr, deg, counts);
    k_dinv<<<nblk_n, 256, 0, stream>>>(deg, selfnorm);
    k_blockreduce<<<NBLK_SCAN, 256, 0, stream>>>(counts, blocksums);
    k_scanblocksums<<<1, 512, 0, stream>>>(blocksums);
    k_blockscan<<<NBLK_SCAN, 256, 0, stream>>>(counts, blocksums, offsets, cursor);
    k_fill<<<nblk_e, 256, 0, stream>>>(src, dst, (const float2*)edge_attr, deg, cursor, csr);

    // ---- layer 0: fused agg8 + mm0 -> r0 (bf16) + stats0 ----
    k_aggmm0<<<nblk_mm, 256, 0, stream>>>(x, offsets, csr, selfnorm, W0, b0, rbuf, stats);

    // ---- layer 1: gather (emits dvec) + mm -> r1 (bf16) + stats1 ----
    k_gather64<<<nblk_g64, 256, 0, stream>>>(rbuf, offsets, csr, selfnorm, aggbuf, dvec);
    k_mm1<<<nblk_mm, 256, 0, stream>>>(aggbuf, dvec, stats, gammas, betas,
                                       Ws, bs, rbuf, stats + 1024);

    // ---- layer 2: gather + mm with fused pooling (r2 stays on-chip) ----
    k_gather64<<<nblk_g64, 256, 0, stream>>>(rbuf, offsets, csr, selfnorm, aggbuf, nullptr);
    k_mm2<<<nblk_mm, 256, 0, stream>>>(aggbuf, dvec, stats + 1024, gammas + 64, betas + 64,
                                       Ws + 64 * 64, bs + 64, batch, pooled, gcount,
                                       stats + 2048);

    // ---- head ----
    k_head<<<NGRAPH, 64, 0, stream>>>(pooled, gcount, stats + 2048,
                                      gammas + 2 * 64, betas + 2 * 64,
                                      lin1_w, lin1_b, lin2_w, lin2_b, out);
}

// Round 8
// 533.512 us; speedup vs baseline: 1.8281x; 1.3014x over previous
//
#include <hip/hip_runtime.h>
#include <math.h>

#define N_NODES 100000
#define N_EDGES 1250000
#define NGRAPH 256
#define IN_DIM 8
#define DIM 64
#define BN_EPS 1e-5f

#define NBLK_SCAN 391  // ceil(100000/256)

typedef unsigned short bf16_t;

static __device__ inline float bf2f(bf16_t u) {
    return __uint_as_float(((unsigned int)u) << 16);
}
static __device__ inline bf16_t f2bf(float f) {
    unsigned int b = __float_as_uint(f);
    b += 0x7fffu + ((b >> 16) & 1u);
    return (bf16_t)(b >> 16);
}

// ---------------- fused degree-sum + in-degree histogram (deg starts at 0) ----------------

__global__ void k_degcnt(const int* __restrict__ dst, const float2* __restrict__ edge_attr,
                         float* __restrict__ deg, int* __restrict__ counts) {
    int e = blockIdx.x * 256 + threadIdx.x;
    if (e < N_EDGES) {
        int d = dst[e];
        atomicAdd(&deg[d], edge_attr[e].y);
        atomicAdd(&counts[d], 1);
    }
}

// dinv + selfnorm (self-loop weight 1 folded in: deg_total = deg + 1 > 0 always)

__global__ void k_dinv(float* __restrict__ deg, float* __restrict__ selfnorm) {
    int i = blockIdx.x * 256 + threadIdx.x;
    if (i < N_NODES) {
        float r = rsqrtf(deg[i] + 1.0f);
        deg[i] = r;
        selfnorm[i] = r * r;
    }
}

// ---------------- CSR build (counting sort by dst) ----------------

__global__ void k_blockreduce(const int* __restrict__ counts, int* __restrict__ blocksums) {
    __shared__ int sh[256];
    int t = threadIdx.x;
    int i = blockIdx.x * 256 + t;
    sh[t] = (i < N_NODES) ? counts[i] : 0;
    __syncthreads();
    for (int off = 128; off > 0; off >>= 1) {
        if (t < off) sh[t] += sh[t + off];
        __syncthreads();
    }
    if (t == 0) blocksums[blockIdx.x] = sh[0];
}

__global__ void k_scanblocksums(int* __restrict__ blocksums) {
    __shared__ int sh[512];
    int t = threadIdx.x;
    int v = (t < NBLK_SCAN) ? blocksums[t] : 0;
    sh[t] = v;
    __syncthreads();
    for (int off = 1; off < 512; off <<= 1) {
        int add = (t >= off) ? sh[t - off] : 0;
        __syncthreads();
        sh[t] += add;
        __syncthreads();
    }
    if (t < NBLK_SCAN) blocksums[t] = sh[t] - v;  // exclusive
}

__global__ void k_blockscan(const int* __restrict__ counts, const int* __restrict__ blocksums,
                            int* __restrict__ offsets, int* __restrict__ cursor) {
    __shared__ int sh[256];
    int t = threadIdx.x;
    int i = blockIdx.x * 256 + t;
    int v = (i < N_NODES) ? counts[i] : 0;
    sh[t] = v;
    __syncthreads();
    for (int off = 1; off < 256; off <<= 1) {
        int add = (t >= off) ? sh[t - off] : 0;
        __syncthreads();
        sh[t] += add;
        __syncthreads();
    }
    int excl = sh[t] - v + blocksums[blockIdx.x];
    if (i < N_NODES) { offsets[i] = excl; cursor[i] = excl; }
    if (i == N_NODES - 1) offsets[N_NODES] = excl + v;  // == E
}

__global__ void k_fill(const int* __restrict__ src, const int* __restrict__ dst,
                       const float2* __restrict__ edge_attr, const float* __restrict__ dinv,
                       int* __restrict__ cursor, int2* __restrict__ csr) {
    int e = blockIdx.x * 256 + threadIdx.x;
    if (e >= N_EDGES) return;
    int s = src[e], d = dst[e];
    float w = edge_attr[e].y;
    int pos = atomicAdd(&cursor[d], 1);
    float nv = dinv[s] * w * dinv[d];
    csr[pos] = make_int2(s, __float_as_int(nv));
}

// ------- fused layer 0: agg (8ch, random 32B rows) + matmul 8x64 + relu + stats -------
// block = 32 nodes x 8 lanes; edge loop unrolled x2 for load ILP.

__global__ void __launch_bounds__(256) k_aggmm0(
        const float* __restrict__ x, const int* __restrict__ offsets,
        const int2* __restrict__ csr, const float* __restrict__ selfnorm,
        const float* __restrict__ W0, const float* __restrict__ b0,
        bf16_t* __restrict__ rout, float* __restrict__ stats) {
    __shared__ float Wsh[IN_DIM * 64];
    __shared__ float bsh[64];
    __shared__ float sstat[64], sq[64];
    int tid = threadIdx.x;
    for (int i = tid; i < IN_DIM * 64; i += 256) Wsh[i] = W0[i];
    if (tid < 64) { bsh[tid] = b0[tid]; sstat[tid] = 0.0f; sq[tid] = 0.0f; }
    __syncthreads();
    int node = blockIdx.x * 32 + (tid >> 3);
    int ch = tid & 7;
    float acc = selfnorm[node] * x[node * 8 + ch];
    int e0 = offsets[node], e1 = offsets[node + 1];
    int e = e0;
    for (; e + 2 <= e1; e += 2) {
        int2 pa = csr[e], pb = csr[e + 1];
        float va = x[pa.x * 8 + ch];
        float vb = x[pb.x * 8 + ch];
        acc = fmaf(__int_as_float(pa.y), va, acc);
        acc = fmaf(__int_as_float(pb.y), vb, acc);
    }
    if (e < e1) {
        int2 p = csr[e];
        acc = fmaf(__int_as_float(p.y), x[p.x * 8 + ch], acc);
    }
    float a[8];
#pragma unroll
    for (int k = 0; k < 8; ++k) a[k] = __shfl(acc, k, 8);
    unsigned int pk[4];
#pragma unroll
    for (int q = 0; q < 4; ++q) {
        float v0, v1;
#pragma unroll
        for (int h = 0; h < 2; ++h) {
            int c = ch * 8 + 2 * q + h;
            float v = bsh[c];
#pragma unroll
            for (int k = 0; k < 8; ++k) v = fmaf(a[k], Wsh[k * 64 + c], v);
            v = fmaxf(v, 0.0f);
            atomicAdd(&sstat[c], v);
            atomicAdd(&sq[c], v * v);
            if (h == 0) v0 = v; else v1 = v;
        }
        pk[q] = (unsigned int)f2bf(v0) | ((unsigned int)f2bf(v1) << 16);
    }
    *(uint4*)(rout + node * 64 + ch * 8) = make_uint4(pk[0], pk[1], pk[2], pk[3]);
    __syncthreads();
    if (tid < 64) {
        int bin = blockIdx.x & 7;
        atomicAdd(&stats[bin * 128 + tid], sstat[tid]);
        atomicAdd(&stats[bin * 128 + 64 + tid], sq[tid]);
    }
}

// ------- 64-ch aggregation: lane-parallel CSR + 8-wide pipelined row loads -------
// One wave per node. Phase 1: 64 lanes cooperatively load up to 64 CSR entries
// (one coalesced load). Phase 2: per 8-edge group, shfl-broadcast 8 (src,nv),
// issue 8 independent 128B row loads, then 8 FMAs. Pad slots = own row, w=0.

__global__ void __launch_bounds__(256) k_gather64(
        const bf16_t* __restrict__ t, const int* __restrict__ offsets,
        const int2* __restrict__ csr, const float* __restrict__ selfnorm,
        float* __restrict__ agg, float* __restrict__ dvec) {
    int wid = (blockIdx.x * 256 + threadIdx.x) >> 6;
    int lane = threadIdx.x & 63;
    if (wid >= N_NODES) return;
    float sn = selfnorm[wid];
    float acc = sn * bf2f(t[(size_t)wid * 64 + lane]);
    float nvpart = 0.0f;
    int e0 = offsets[wid], e1 = offsets[wid + 1];
    for (int base = e0; base < e1; base += 64) {
        int n = e1 - base;
        n = (n > 64) ? 64 : n;
        int2 pe = make_int2(wid, 0);  // pad: own row, weight 0
        if (lane < n) pe = csr[base + lane];
        nvpart += __int_as_float(pe.y);
        int ng = (n + 7) >> 3;
        for (int g = 0; g < ng; ++g) {
            int j = g * 8;
            int s[8];
            float w[8];
#pragma unroll
            for (int u = 0; u < 8; ++u) {
                s[u] = __shfl(pe.x, j + u, 64);
                w[u] = __int_as_float(__shfl(pe.y, j + u, 64));
            }
            float v[8];
#pragma unroll
            for (int u = 0; u < 8; ++u) v[u] = bf2f(t[(size_t)s[u] * 64 + lane]);
#pragma unroll
            for (int u = 0; u < 8; ++u) acc = fmaf(w[u], v[u], acc);
        }
    }
    agg[(size_t)wid * 64 + lane] = acc;
    if (dvec != nullptr) {
#pragma unroll
        for (int off = 32; off > 0; off >>= 1) nvpart += __shfl_xor(nvpart, off, 64);
        if (lane == 0) dvec[wid] = sn + nvpart;
    }
}

// ------- mid layer matmul: r' = relu((AGG*sc + dvec*sh) @ W + b), bf16 out, stats -------
// inner loop: 4-k step, float4 broadcast reads of hsh (wave-uniform address).

__global__ void __launch_bounds__(256) k_mm1(
        const float* __restrict__ agg, const float* __restrict__ dvec,
        const float* __restrict__ statsin, const float* __restrict__ gamma,
        const float* __restrict__ beta, const float* __restrict__ W,
        const float* __restrict__ bias, bf16_t* __restrict__ rout,
        float* __restrict__ statsout) {
    __shared__ float Wsh[64 * 64];
    __shared__ float hsh[32 * 64];
    __shared__ float scs[64], shs[64];
    __shared__ float s1[256], s2[256];
    int tid = threadIdx.x;
    if (tid < 64) {
        float s = 0.0f, q = 0.0f;
#pragma unroll
        for (int b = 0; b < 8; ++b) {
            s += statsin[b * 128 + tid];
            q += statsin[b * 128 + 64 + tid];
        }
        const float invn = 1.0f / (float)N_NODES;
        float mu = s * invn;
        float var = q * invn - mu * mu;
        float rs = rsqrtf(var + BN_EPS);
        float sc = gamma[tid] * rs;
        scs[tid] = sc;
        shs[tid] = beta[tid] - sc * mu;
    }
    {
        const float4* W4 = (const float4*)W;
        float4* Wsh4 = (float4*)Wsh;
        for (int i = tid; i < 1024; i += 256) Wsh4[i] = W4[i];
    }
    __syncthreads();
    int row0 = blockIdx.x * 32;
    {
        const float4* a4 = (const float4*)(agg + (size_t)row0 * 64);
        float4* h4 = (float4*)hsh;
        for (int i = tid; i < 512; i += 256) {
            float4 a = a4[i];
            int kk = (i * 4) & 63;
            int rr = (i * 4) >> 6;
            float dv = dvec[row0 + rr];
            h4[i] = make_float4(a.x * scs[kk] + dv * shs[kk],
                                a.y * scs[kk + 1] + dv * shs[kk + 1],
                                a.z * scs[kk + 2] + dv * shs[kk + 2],
                                a.w * scs[kk + 3] + dv * shs[kk + 3]);
        }
    }
    __syncthreads();
    int c = tid & 63, rsl = tid >> 6;
    float b_c = bias[c];
    float acc[8];
#pragma unroll
    for (int j = 0; j < 8; ++j) acc[j] = 0.0f;
    for (int k = 0; k < 64; k += 4) {
        float w0 = Wsh[(k + 0) * 64 + c];
        float w1 = Wsh[(k + 1) * 64 + c];
        float w2 = Wsh[(k + 2) * 64 + c];
        float w3 = Wsh[(k + 3) * 64 + c];
#pragma unroll
        for (int j = 0; j < 8; ++j) {
            float4 hv = *(const float4*)&hsh[(rsl * 8 + j) * 64 + k];
            acc[j] = fmaf(hv.x, w0, fmaf(hv.y, w1, fmaf(hv.z, w2, fmaf(hv.w, w3, acc[j]))));
        }
    }
    float sum = 0.0f, ssq = 0.0f;
#pragma unroll
    for (int j = 0; j < 8; ++j) {
        float v = fmaxf(acc[j] + b_c, 0.0f);
        rout[(size_t)(row0 + rsl * 8 + j) * 64 + c] = f2bf(v);
        sum += v;
        ssq += v * v;
    }
    s1[tid] = sum; s2[tid] = ssq;
    __syncthreads();
    if (tid < 64) {
        int bin = blockIdx.x & 7;
        atomicAdd(&statsout[bin * 128 + tid],
                  s1[tid] + s1[tid + 64] + s1[tid + 128] + s1[tid + 192]);
        atomicAdd(&statsout[bin * 128 + 64 + tid],
                  s2[tid] + s2[tid + 64] + s2[tid + 128] + s2[tid + 192]);
    }
}

// ------- final layer matmul + fused pooling: r2 never touches global memory -------

__global__ void __launch_bounds__(256) k_mm2(
        const float* __restrict__ agg, const float* __restrict__ dvec,
        const float* __restrict__ statsin, const float* __restrict__ gamma,
        const float* __restrict__ beta, const float* __restrict__ W,
        const float* __restrict__ bias, const int* __restrict__ batch,
        float* __restrict__ pooled, int* __restrict__ gcount,
        float* __restrict__ statsout) {
    __shared__ float Wsh[64 * 64];
    __shared__ float hsh[32 * 64];
    __shared__ float rt[32 * 64];
    __shared__ float scs[64], shs[64];
    __shared__ float s1[256], s2[256];
    __shared__ int sbatch[32];
    int tid = threadIdx.x;
    int row0 = blockIdx.x * 32;
    if (tid < 64) {
        float s = 0.0f, q = 0.0f;
#pragma unroll
        for (int b = 0; b < 8; ++b) {
            s += statsin[b * 128 + tid];
            q += statsin[b * 128 + 64 + tid];
        }
        const float invn = 1.0f / (float)N_NODES;
        float mu = s * invn;
        float var = q * invn - mu * mu;
        float rs = rsqrtf(var + BN_EPS);
        float sc = gamma[tid] * rs;
        scs[tid] = sc;
        shs[tid] = beta[tid] - sc * mu;
    }
    if (tid >= 64 && tid < 96) sbatch[tid - 64] = batch[row0 + tid - 64];
    {
        const float4* W4 = (const float4*)W;
        float4* Wsh4 = (float4*)Wsh;
        for (int i = tid; i < 1024; i += 256) Wsh4[i] = W4[i];
    }
    __syncthreads();
    {
        const float4* a4 = (const float4*)(agg + (size_t)row0 * 64);
        float4* h4 = (float4*)hsh;
        for (int i = tid; i < 512; i += 256) {
            float4 a = a4[i];
            int kk = (i * 4) & 63;
            int rr = (i * 4) >> 6;
            float dv = dvec[row0 + rr];
            h4[i] = make_float4(a.x * scs[kk] + dv * shs[kk],
                                a.y * scs[kk + 1] + dv * shs[kk + 1],
                                a.z * scs[kk + 2] + dv * shs[kk + 2],
                                a.w * scs[kk + 3] + dv * shs[kk + 3]);
        }
    }
    __syncthreads();
    int c = tid & 63, rsl = tid >> 6;
    float b_c = bias[c];
    float acc[8];
#pragma unroll
    for (int j = 0; j < 8; ++j) acc[j] = 0.0f;
    for (int k = 0; k < 64; k += 4) {
        float w0 = Wsh[(k + 0) * 64 + c];
        float w1 = Wsh[(k + 1) * 64 + c];
        float w2 = Wsh[(k + 2) * 64 + c];
        float w3 = Wsh[(k + 3) * 64 + c];
#pragma unroll
        for (int j = 0; j < 8; ++j) {
            float4 hv = *(const float4*)&hsh[(rsl * 8 + j) * 64 + k];
            acc[j] = fmaf(hv.x, w0, fmaf(hv.y, w1, fmaf(hv.z, w2, fmaf(hv.w, w3, acc[j]))));
        }
    }
    float sum = 0.0f, ssq = 0.0f;
#pragma unroll
    for (int j = 0; j < 8; ++j) {
        float v = fmaxf(acc[j] + b_c, 0.0f);
        rt[(rsl * 8 + j) * 64 + c] = v;
        sum += v;
        ssq += v * v;
    }
    s1[tid] = sum; s2[tid] = ssq;
    __syncthreads();
    if (tid < 64) {
        int cur = sbatch[0], cnt = 0;
        float a = 0.0f;
        for (int r = 0; r < 32; ++r) {
            int g = sbatch[r];
            if (g != cur) {
                atomicAdd(&pooled[cur * 64 + c], a);
                if (c == 0) atomicAdd(&gcount[cur], cnt);
                cur = g; a = 0.0f; cnt = 0;
            }
            a += rt[r * 64 + c];
            cnt += 1;
        }
        atomicAdd(&pooled[cur * 64 + c], a);
        if (c == 0) atomicAdd(&gcount[cur], cnt);
        int bin = blockIdx.x & 7;
        atomicAdd(&statsout[bin * 128 + tid],
                  s1[tid] + s1[tid + 64] + s1[tid + 128] + s1[tid + 192]);
        atomicAdd(&statsout[bin * 128 + 64 + tid],
                  s2[tid] + s2[tid + 64] + s2[tid + 128] + s2[tid + 192]);
    }
}

// ------- head: BN affine from binned stats folded via counts, mlp, log_softmax -------

__global__ void k_head(const float* __restrict__ pooled, const int* __restrict__ gcount,
                       const float* __restrict__ stats, const float* __restrict__ gamma,
                       const float* __restrict__ beta, const float* __restrict__ w1,
                       const float* __restrict__ b1, const float* __restrict__ w2,
                       const float* __restrict__ b2, float* __restrict__ out) {
    __shared__ float p[64];
    __shared__ float hid[64];
    __shared__ float o[2];
    int g = blockIdx.x, c = threadIdx.x;
    float s = 0.0f, q = 0.0f;
#pragma unroll
    for (int b = 0; b < 8; ++b) {
        s += stats[b * 128 + c];
        q += stats[b * 128 + 64 + c];
    }
    const float invn = 1.0f / (float)N_NODES;
    float mu = s * invn;
    float var = q * invn - mu * mu;
    float rs = rsqrtf(var + BN_EPS);
    float sc = gamma[c] * rs;
    float sh = beta[c] - sc * mu;
    p[c] = sc * pooled[g * 64 + c] + (float)gcount[g] * sh;
    __syncthreads();
    float acc = b1[c];
#pragma unroll
    for (int k = 0; k < 64; ++k) acc += p[k] * w1[k * 64 + c];
    hid[c] = fmaxf(acc, 0.0f);
    __syncthreads();
    if (c < 2) {
        float a = b2[c];
#pragma unroll
        for (int k = 0; k < 64; ++k) a += hid[k] * w2[k * 2 + c];
        o[c] = a;
    }
    __syncthreads();
    if (c == 0) {
        float m = fmaxf(o[0], o[1]);
        float l = m + logf(expf(o[0] - m) + expf(o[1] - m));
        out[g * 2 + 0] = o[0] - l;
        out[g * 2 + 1] = o[1] - l;
    }
}

extern "C" void kernel_launch(void* const* d_in, const int* in_sizes, int n_in,
                              void* d_out, int out_size, void* d_ws, size_t ws_size,
                              hipStream_t stream) {
    const float* x        = (const float*)d_in[0];
    const int*   ei       = (const int*)d_in[1];
    const int*   batch    = (const int*)d_in[2];
    const float* edge_attr= (const float*)d_in[3];
    const float* W0       = (const float*)d_in[4];
    const float* b0       = (const float*)d_in[5];
    const float* Ws       = (const float*)d_in[6];
    const float* bs       = (const float*)d_in[7];
    const float* gammas   = (const float*)d_in[8];
    const float* betas    = (const float*)d_in[9];
    const float* lin1_w   = (const float*)d_in[10];
    const float* lin1_b   = (const float*)d_in[11];
    const float* lin2_w   = (const float*)d_in[12];
    const float* lin2_b   = (const float*)d_in[13];
    float* out = (float*)d_out;

    const int* src = ei;
    const int* dst = ei + N_EDGES;

    // workspace layout (float units)
    float*  ws0      = (float*)d_ws;
    float*  selfnorm = ws0;                             // 100000
    int*    offsets  = (int*)(ws0 + 100000);            // 100001, pad to 100004
    float*  dvec     = ws0 + 200004;                    // 100000
    int2*   csr      = (int2*)(ws0 + 300004);           // 2.5M floats
    bf16_t* rbuf     = (bf16_t*)(ws0 + 2800004);        // N*64 bf16 = 3.2M floats
    float*  aggbuf   = ws0 + 6000004;                   // N*64 fp32 = 6.4M floats
    float*  stats    = aggbuf + (size_t)N_NODES * 64;   // 3*1024
    float*  pooled   = stats + 3 * 1024;                // 16384
    int*    gcount   = (int*)(pooled + NGRAPH * 64);    // 256
    // transient CSR-build aliases inside aggbuf (dead before gather#1 writes it)
    float* deg       = aggbuf;                          // 100000
    int*   counts    = (int*)(aggbuf + 100000);         // 100000 (adjacent to deg)
    int*   cursor    = (int*)(aggbuf + 200000);         // 100000
    int*   blocksums = (int*)(aggbuf + 300000);         // 512

    const int nblk_n = (N_NODES + 255) / 256;        // 391
    const int nblk_e = (N_EDGES + 255) / 256;        // 4883
    const int nblk_g64 = N_NODES * 64 / 256;         // 25000
    const int nblk_mm = N_NODES / 32;                // 3125

    // zero deg+counts (adjacent) and stats+pooled+gcount (adjacent)
    hipMemsetAsync(deg, 0, 200000 * sizeof(float), stream);
    hipMemsetAsync(stats, 0, (3 * 1024 + NGRAPH * 64 + NGRAPH) * sizeof(float), stream);

    // ---- degree / dinv / selfnorm + CSR build ----
    k_degcnt<<<nblk_e, 256, 0, stream>>>(dst, (const float2*)edge_attr, deg, counts);
    k_dinv<<<nblk_n, 256, 0, stream>>>(deg, selfnorm);
    k_blockreduce<<<NBLK_SCAN, 256, 0, stream>>>(counts, blocksums);
    k_scanblocksums<<<1, 512, 0, stream>>>(blocksums);
    k_blockscan<<<NBLK_SCAN, 256, 0, stream>>>(counts, blocksums, offsets, cursor);
    k_fill<<<nblk_e, 256, 0, stream>>>(src, dst, (const float2*)edge_attr, deg, cursor, csr);

    // ---- layer 0: fused agg8 + mm0 -> r0 (bf16) + stats0 ----
    k_aggmm0<<<nblk_mm, 256, 0, stream>>>(x, offsets, csr, selfnorm, W0, b0, rbuf, stats);

    // ---- layer 1: gather (emits dvec) + mm -> r1 (bf16) + stats1 ----
    k_gather64<<<nblk_g64, 256, 0, stream>>>(rbuf, offsets, csr, selfnorm, aggbuf, dvec);
    k_mm1<<<nblk_mm, 256, 0, stream>>>(aggbuf, dvec, stats, gammas, betas,
                                       Ws, bs, rbuf, stats + 1024);

    // ---- layer 2: gather + mm with fused pooling (r2 stays on-chip) ----
    k_gather64<<<nblk_g64, 256, 0, stream>>>(rbuf, offsets, csr, selfnorm, aggbuf, nullptr);
    k_mm2<<<nblk_mm, 256, 0, stream>>>(aggbuf, dvec, stats + 1024, gammas + 64, betas + 64,
                                       Ws + 64 * 64, bs + 64, batch, pooled, gcount,
                                       stats + 2048);

    // ---- head ----
    k_head<<<NGRAPH, 64, 0, stream>>>(pooled, gcount, stats + 2048,
                                      gammas + 2 * 64, betas + 2 * 64,
                                      lin1_w, lin1_b, lin2_w, lin2_b, out);
}

// Round 9
// 516.262 us; speedup vs baseline: 1.8892x; 1.0334x over previous
//
#include <hip/hip_runtime.h>
#include <math.h>

#define N_NODES 100000
#define N_EDGES 1250000
#define NGRAPH 256
#define IN_DIM 8
#define DIM 64
#define BN_EPS 1e-5f

#define NBLK_SCAN 391  // ceil(100000/256)

typedef unsigned short bf16_t;

static __device__ inline float bf2f(bf16_t u) {
    return __uint_as_float(((unsigned int)u) << 16);
}
static __device__ inline bf16_t f2bf(float f) {
    unsigned int b = __float_as_uint(f);
    b += 0x7fffu + ((b >> 16) & 1u);
    return (bf16_t)(b >> 16);
}

// ---------------- in-degree histogram (counts only; deg comes later, atomic-free) ----------------

__global__ void k_hist(const int* __restrict__ dst, int* __restrict__ counts) {
    int e = blockIdx.x * 256 + threadIdx.x;
    if (e < N_EDGES) atomicAdd(&counts[dst[e]], 1);
}

// ---------------- CSR build (counting sort by dst) ----------------

__global__ void k_blockreduce(const int* __restrict__ counts, int* __restrict__ blocksums) {
    __shared__ int sh[256];
    int t = threadIdx.x;
    int i = blockIdx.x * 256 + t;
    sh[t] = (i < N_NODES) ? counts[i] : 0;
    __syncthreads();
    for (int off = 128; off > 0; off >>= 1) {
        if (t < off) sh[t] += sh[t + off];
        __syncthreads();
    }
    if (t == 0) blocksums[blockIdx.x] = sh[0];
}

__global__ void k_scanblocksums(int* __restrict__ blocksums) {
    __shared__ int sh[512];
    int t = threadIdx.x;
    int v = (t < NBLK_SCAN) ? blocksums[t] : 0;
    sh[t] = v;
    __syncthreads();
    for (int off = 1; off < 512; off <<= 1) {
        int add = (t >= off) ? sh[t - off] : 0;
        __syncthreads();
        sh[t] += add;
        __syncthreads();
    }
    if (t < NBLK_SCAN) blocksums[t] = sh[t] - v;  // exclusive
}

__global__ void k_blockscan(const int* __restrict__ counts, const int* __restrict__ blocksums,
                            int* __restrict__ offsets, int* __restrict__ cursor) {
    __shared__ int sh[256];
    int t = threadIdx.x;
    int i = blockIdx.x * 256 + t;
    int v = (i < N_NODES) ? counts[i] : 0;
    sh[t] = v;
    __syncthreads();
    for (int off = 1; off < 256; off <<= 1) {
        int add = (t >= off) ? sh[t - off] : 0;
        __syncthreads();
        sh[t] += add;
        __syncthreads();
    }
    int excl = sh[t] - v + blocksums[blockIdx.x];
    if (i < N_NODES) { offsets[i] = excl; cursor[i] = excl; }
    if (i == N_NODES - 1) offsets[N_NODES] = excl + v;  // == E
}

// fill with RAW (src, w); nv computed after segment degrees are known

__global__ void k_fill(const int* __restrict__ src, const int* __restrict__ dst,
                       const float2* __restrict__ edge_attr, int* __restrict__ cursor,
                       int2* __restrict__ csr) {
    int e = blockIdx.x * 256 + threadIdx.x;
    if (e >= N_EDGES) return;
    int s = src[e], d = dst[e];
    float w = edge_attr[e].y;
    int pos = atomicAdd(&cursor[d], 1);
    csr[pos] = make_int2(s, __float_as_int(w));
}

// ------- segment degree: deg[d] = sum w over sorted segment (no atomics) -------
// one wave per node; lanes stride the segment (coalesced int2 reads).

__global__ void __launch_bounds__(256) k_segnorm(
        const int* __restrict__ offsets, const int2* __restrict__ csr,
        float* __restrict__ dinv, float* __restrict__ selfnorm) {
    int wid = (blockIdx.x * 256 + threadIdx.x) >> 6;
    int lane = threadIdx.x & 63;
    if (wid >= N_NODES) return;
    int e0 = offsets[wid], e1 = offsets[wid + 1];
    float part = 0.0f;
    for (int e = e0 + lane; e < e1; e += 64) part += __int_as_float(csr[e].y);
#pragma unroll
    for (int off = 32; off > 0; off >>= 1) part += __shfl_xor(part, off, 64);
    if (lane == 0) {
        float r = rsqrtf(part + 1.0f);  // +1 = self-loop weight
        dinv[wid] = r;
        selfnorm[wid] = r * r;
    }
}

// ------- rescale csr in place: w -> nv = dinv[s]*w*dinv[d]; emit dvec row-sums -------

__global__ void __launch_bounds__(256) k_rescale(
        const int* __restrict__ offsets, int2* __restrict__ csr,
        const float* __restrict__ dinv, const float* __restrict__ selfnorm,
        float* __restrict__ dvec) {
    int wid = (blockIdx.x * 256 + threadIdx.x) >> 6;
    int lane = threadIdx.x & 63;
    if (wid >= N_NODES) return;
    int e0 = offsets[wid], e1 = offsets[wid + 1];
    float dvd = dinv[wid];
    float part = 0.0f;
    for (int e = e0 + lane; e < e1; e += 64) {
        int2 p = csr[e];
        float nv = dinv[p.x] * __int_as_float(p.y) * dvd;
        csr[e] = make_int2(p.x, __float_as_int(nv));
        part += nv;
    }
#pragma unroll
    for (int off = 32; off > 0; off >>= 1) part += __shfl_xor(part, off, 64);
    if (lane == 0) dvec[wid] = selfnorm[wid] + part;
}

// ------- fused layer 0: agg (8ch) + matmul 8x64 + relu + stats -------
// block = 32 nodes x 8 lanes. Edge phase: lane-parallel CSR (8 entries per
// group load, contiguous across the block's 32 segments) + width-8 shfl
// broadcast -> 8 independent x-row loads in flight. Pad: own row, w=0.

__global__ void __launch_bounds__(256) k_aggmm0(
        const float* __restrict__ x, const int* __restrict__ offsets,
        const int2* __restrict__ csr, const float* __restrict__ selfnorm,
        const float* __restrict__ W0, const float* __restrict__ b0,
        bf16_t* __restrict__ rout, float* __restrict__ stats) {
    __shared__ float Wsh[IN_DIM * 64];
    __shared__ float bsh[64];
    __shared__ float sstat[64], sq[64];
    int tid = threadIdx.x;
    for (int i = tid; i < IN_DIM * 64; i += 256) Wsh[i] = W0[i];
    if (tid < 64) { bsh[tid] = b0[tid]; sstat[tid] = 0.0f; sq[tid] = 0.0f; }
    __syncthreads();
    int node = blockIdx.x * 32 + (tid >> 3);
    int ch = tid & 7;
    float acc = selfnorm[node] * x[node * 8 + ch];
    int e0 = offsets[node], e1 = offsets[node + 1];
    for (int base = e0; base < e1; base += 8) {
        int n = e1 - base;
        n = (n > 8) ? 8 : n;
        int2 pe = (ch < n) ? csr[base + ch] : make_int2(node, 0);
        int s[8];
        float w[8], v[8];
#pragma unroll
        for (int u = 0; u < 8; ++u) {
            s[u] = __shfl(pe.x, u, 8);
            w[u] = __int_as_float(__shfl(pe.y, u, 8));
        }
#pragma unroll
        for (int u = 0; u < 8; ++u) v[u] = x[s[u] * 8 + ch];
#pragma unroll
        for (int u = 0; u < 8; ++u) acc = fmaf(w[u], v[u], acc);
    }
    float a[8];
#pragma unroll
    for (int k = 0; k < 8; ++k) a[k] = __shfl(acc, k, 8);
    unsigned int pk[4];
#pragma unroll
    for (int q = 0; q < 4; ++q) {
        float v0, v1;
#pragma unroll
        for (int h = 0; h < 2; ++h) {
            int c = ch * 8 + 2 * q + h;
            float v = bsh[c];
#pragma unroll
            for (int k = 0; k < 8; ++k) v = fmaf(a[k], Wsh[k * 64 + c], v);
            v = fmaxf(v, 0.0f);
            atomicAdd(&sstat[c], v);
            atomicAdd(&sq[c], v * v);
            if (h == 0) v0 = v; else v1 = v;
        }
        pk[q] = (unsigned int)f2bf(v0) | ((unsigned int)f2bf(v1) << 16);
    }
    *(uint4*)(rout + node * 64 + ch * 8) = make_uint4(pk[0], pk[1], pk[2], pk[3]);
    __syncthreads();
    if (tid < 64) {
        int bin = blockIdx.x & 7;
        atomicAdd(&stats[bin * 128 + tid], sstat[tid]);
        atomicAdd(&stats[bin * 128 + 64 + tid], sq[tid]);
    }
}

// ------- 64-ch aggregation: lane-parallel CSR + 8-wide pipelined row loads -------

__global__ void __launch_bounds__(256) k_gather64(
        const bf16_t* __restrict__ t, const int* __restrict__ offsets,
        const int2* __restrict__ csr, const float* __restrict__ selfnorm,
        float* __restrict__ agg) {
    int wid = (blockIdx.x * 256 + threadIdx.x) >> 6;
    int lane = threadIdx.x & 63;
    if (wid >= N_NODES) return;
    float acc = selfnorm[wid] * bf2f(t[(size_t)wid * 64 + lane]);
    int e0 = offsets[wid], e1 = offsets[wid + 1];
    for (int base = e0; base < e1; base += 64) {
        int n = e1 - base;
        n = (n > 64) ? 64 : n;
        int2 pe = make_int2(wid, 0);  // pad: own row, weight 0
        if (lane < n) pe = csr[base + lane];
        int ng = (n + 7) >> 3;
        for (int g = 0; g < ng; ++g) {
            int j = g * 8;
            int s[8];
            float w[8];
#pragma unroll
            for (int u = 0; u < 8; ++u) {
                s[u] = __shfl(pe.x, j + u, 64);
                w[u] = __int_as_float(__shfl(pe.y, j + u, 64));
            }
            float v[8];
#pragma unroll
            for (int u = 0; u < 8; ++u) v[u] = bf2f(t[(size_t)s[u] * 64 + lane]);
#pragma unroll
            for (int u = 0; u < 8; ++u) acc = fmaf(w[u], v[u], acc);
        }
    }
    agg[(size_t)wid * 64 + lane] = acc;
}

// ------- mid layer matmul: r' = relu((AGG*sc + dvec*sh) @ W + b), bf16 out, stats -------

__global__ void __launch_bounds__(256) k_mm1(
        const float* __restrict__ agg, const float* __restrict__ dvec,
        const float* __restrict__ statsin, const float* __restrict__ gamma,
        const float* __restrict__ beta, const float* __restrict__ W,
        const float* __restrict__ bias, bf16_t* __restrict__ rout,
        float* __restrict__ statsout) {
    __shared__ float Wsh[64 * 64];
    __shared__ float hsh[32 * 64];
    __shared__ float scs[64], shs[64];
    __shared__ float s1[256], s2[256];
    int tid = threadIdx.x;
    if (tid < 64) {
        float s = 0.0f, q = 0.0f;
#pragma unroll
        for (int b = 0; b < 8; ++b) {
            s += statsin[b * 128 + tid];
            q += statsin[b * 128 + 64 + tid];
        }
        const float invn = 1.0f / (float)N_NODES;
        float mu = s * invn;
        float var = q * invn - mu * mu;
        float rs = rsqrtf(var + BN_EPS);
        float sc = gamma[tid] * rs;
        scs[tid] = sc;
        shs[tid] = beta[tid] - sc * mu;
    }
    {
        const float4* W4 = (const float4*)W;
        float4* Wsh4 = (float4*)Wsh;
        for (int i = tid; i < 1024; i += 256) Wsh4[i] = W4[i];
    }
    __syncthreads();
    int row0 = blockIdx.x * 32;
    {
        const float4* a4 = (const float4*)(agg + (size_t)row0 * 64);
        float4* h4 = (float4*)hsh;
        for (int i = tid; i < 512; i += 256) {
            float4 a = a4[i];
            int kk = (i * 4) & 63;
            int rr = (i * 4) >> 6;
            float dv = dvec[row0 + rr];
            h4[i] = make_float4(a.x * scs[kk] + dv * shs[kk],
                                a.y * scs[kk + 1] + dv * shs[kk + 1],
                                a.z * scs[kk + 2] + dv * shs[kk + 2],
                                a.w * scs[kk + 3] + dv * shs[kk + 3]);
        }
    }
    __syncthreads();
    int c = tid & 63, rsl = tid >> 6;
    float b_c = bias[c];
    float acc[8];
#pragma unroll
    for (int j = 0; j < 8; ++j) acc[j] = 0.0f;
    for (int k = 0; k < 64; k += 4) {
        float w0 = Wsh[(k + 0) * 64 + c];
        float w1 = Wsh[(k + 1) * 64 + c];
        float w2 = Wsh[(k + 2) * 64 + c];
        float w3 = Wsh[(k + 3) * 64 + c];
#pragma unroll
        for (int j = 0; j < 8; ++j) {
            float4 hv = *(const float4*)&hsh[(rsl * 8 + j) * 64 + k];
            acc[j] = fmaf(hv.x, w0, fmaf(hv.y, w1, fmaf(hv.z, w2, fmaf(hv.w, w3, acc[j]))));
        }
    }
    float sum = 0.0f, ssq = 0.0f;
#pragma unroll
    for (int j = 0; j < 8; ++j) {
        float v = fmaxf(acc[j] + b_c, 0.0f);
        rout[(size_t)(row0 + rsl * 8 + j) * 64 + c] = f2bf(v);
        sum += v;
        ssq += v * v;
    }
    s1[tid] = sum; s2[tid] = ssq;
    __syncthreads();
    if (tid < 64) {
        int bin = blockIdx.x & 7;
        atomicAdd(&statsout[bin * 128 + tid],
                  s1[tid] + s1[tid + 64] + s1[tid + 128] + s1[tid + 192]);
        atomicAdd(&statsout[bin * 128 + 64 + tid],
                  s2[tid] + s2[tid + 64] + s2[tid + 128] + s2[tid + 192]);
    }
}

// ------- final layer matmul + fused pooling: r2 never touches global memory -------

__global__ void __launch_bounds__(256) k_mm2(
        const float* __restrict__ agg, const float* __restrict__ dvec,
        const float* __restrict__ statsin, const float* __restrict__ gamma,
        const float* __restrict__ beta, const float* __restrict__ W,
        const float* __restrict__ bias, const int* __restrict__ batch,
        float* __restrict__ pooled, int* __restrict__ gcount,
        float* __restrict__ statsout) {
    __shared__ float Wsh[64 * 64];
    __shared__ float hsh[32 * 64];
    __shared__ float rt[32 * 64];
    __shared__ float scs[64], shs[64];
    __shared__ float s1[256], s2[256];
    __shared__ int sbatch[32];
    int tid = threadIdx.x;
    int row0 = blockIdx.x * 32;
    if (tid < 64) {
        float s = 0.0f, q = 0.0f;
#pragma unroll
        for (int b = 0; b < 8; ++b) {
            s += statsin[b * 128 + tid];
            q += statsin[b * 128 + 64 + tid];
        }
        const float invn = 1.0f / (float)N_NODES;
        float mu = s * invn;
        float var = q * invn - mu * mu;
        float rs = rsqrtf(var + BN_EPS);
        float sc = gamma[tid] * rs;
        scs[tid] = sc;
        shs[tid] = beta[tid] - sc * mu;
    }
    if (tid >= 64 && tid < 96) sbatch[tid - 64] = batch[row0 + tid - 64];
    {
        const float4* W4 = (const float4*)W;
        float4* Wsh4 = (float4*)Wsh;
        for (int i = tid; i < 1024; i += 256) Wsh4[i] = W4[i];
    }
    __syncthreads();
    {
        const float4* a4 = (const float4*)(agg + (size_t)row0 * 64);
        float4* h4 = (float4*)hsh;
        for (int i = tid; i < 512; i += 256) {
            float4 a = a4[i];
            int kk = (i * 4) & 63;
            int rr = (i * 4) >> 6;
            float dv = dvec[row0 + rr];
            h4[i] = make_float4(a.x * scs[kk] + dv * shs[kk],
                                a.y * scs[kk + 1] + dv * shs[kk + 1],
                                a.z * scs[kk + 2] + dv * shs[kk + 2],
                                a.w * scs[kk + 3] + dv * shs[kk + 3]);
        }
    }
    __syncthreads();
    int c = tid & 63, rsl = tid >> 6;
    float b_c = bias[c];
    float acc[8];
#pragma unroll
    for (int j = 0; j < 8; ++j) acc[j] = 0.0f;
    for (int k = 0; k < 64; k += 4) {
        float w0 = Wsh[(k + 0) * 64 + c];
        float w1 = Wsh[(k + 1) * 64 + c];
        float w2 = Wsh[(k + 2) * 64 + c];
        float w3 = Wsh[(k + 3) * 64 + c];
#pragma unroll
        for (int j = 0; j < 8; ++j) {
            float4 hv = *(const float4*)&hsh[(rsl * 8 + j) * 64 + k];
            acc[j] = fmaf(hv.x, w0, fmaf(hv.y, w1, fmaf(hv.z, w2, fmaf(hv.w, w3, acc[j]))));
        }
    }
    float sum = 0.0f, ssq = 0.0f;
#pragma unroll
    for (int j = 0; j < 8; ++j) {
        float v = fmaxf(acc[j] + b_c, 0.0f);
        rt[(rsl * 8 + j) * 64 + c] = v;
        sum += v;
        ssq += v * v;
    }
    s1[tid] = sum; s2[tid] = ssq;
    __syncthreads();
    if (tid < 64) {
        int cur = sbatch[0], cnt = 0;
        float a = 0.0f;
        for (int r = 0; r < 32; ++r) {
            int g = sbatch[r];
            if (g != cur) {
                atomicAdd(&pooled[cur * 64 + c], a);
                if (c == 0) atomicAdd(&gcount[cur], cnt);
                cur = g; a = 0.0f; cnt = 0;
            }
            a += rt[r * 64 + c];
            cnt += 1;
        }
        atomicAdd(&pooled[cur * 64 + c], a);
        if (c == 0) atomicAdd(&gcount[cur], cnt);
        int bin = blockIdx.x & 7;
        atomicAdd(&statsout[bin * 128 + tid],
                  s1[tid] + s1[tid + 64] + s1[tid + 128] + s1[tid + 192]);
        atomicAdd(&statsout[bin * 128 + 64 + tid],
                  s2[tid] + s2[tid + 64] + s2[tid + 128] + s2[tid + 192]);
    }
}

// ------- head: BN affine from binned stats folded via counts, mlp, log_softmax -------

__global__ void k_head(const float* __restrict__ pooled, const int* __restrict__ gcount,
                       const float* __restrict__ stats, const float* __restrict__ gamma,
                       const float* __restrict__ beta, const float* __restrict__ w1,
                       const float* __restrict__ b1, const float* __restrict__ w2,
                       const float* __restrict__ b2, float* __restrict__ out) {
    __shared__ float p[64];
    __shared__ float hid[64];
    __shared__ float o[2];
    int g = blockIdx.x, c = threadIdx.x;
    float s = 0.0f, q = 0.0f;
#pragma unroll
    for (int b = 0; b < 8; ++b) {
        s += stats[b * 128 + c];
        q += stats[b * 128 + 64 + c];
    }
    const float invn = 1.0f / (float)N_NODES;
    float mu = s * invn;
    float var = q * invn - mu * mu;
    float rs = rsqrtf(var + BN_EPS);
    float sc = gamma[c] * rs;
    float sh = beta[c] - sc * mu;
    p[c] = sc * pooled[g * 64 + c] + (float)gcount[g] * sh;
    __syncthreads();
    float acc = b1[c];
#pragma unroll
    for (int k = 0; k < 64; ++k) acc += p[k] * w1[k * 64 + c];
    hid[c] = fmaxf(acc, 0.0f);
    __syncthreads();
    if (c < 2) {
        float a = b2[c];
#pragma unroll
        for (int k = 0; k < 64; ++k) a += hid[k] * w2[k * 2 + c];
        o[c] = a;
    }
    __syncthreads();
    if (c == 0) {
        float m = fmaxf(o[0], o[1]);
        float l = m + logf(expf(o[0] - m) + expf(o[1] - m));
        out[g * 2 + 0] = o[0] - l;
        out[g * 2 + 1] = o[1] - l;
    }
}

extern "C" void kernel_launch(void* const* d_in, const int* in_sizes, int n_in,
                              void* d_out, int out_size, void* d_ws, size_t ws_size,
                              hipStream_t stream) {
    const float* x        = (const float*)d_in[0];
    const int*   ei       = (const int*)d_in[1];
    const int*   batch    = (const int*)d_in[2];
    const float* edge_attr= (const float*)d_in[3];
    const float* W0       = (const float*)d_in[4];
    const float* b0       = (const float*)d_in[5];
    const float* Ws       = (const float*)d_in[6];
    const float* bs       = (const float*)d_in[7];
    const float* gammas   = (const float*)d_in[8];
    const float* betas    = (const float*)d_in[9];
    const float* lin1_w   = (const float*)d_in[10];
    const float* lin1_b   = (const float*)d_in[11];
    const float* lin2_w   = (const float*)d_in[12];
    const float* lin2_b   = (const float*)d_in[13];
    float* out = (float*)d_out;

    const int* src = ei;
    const int* dst = ei + N_EDGES;

    // workspace layout (float units)
    float*  ws0      = (float*)d_ws;
    float*  selfnorm = ws0;                             // 100000
    int*    offsets  = (int*)(ws0 + 100000);            // 100001, pad to 100004
    float*  dvec     = ws0 + 200004;                    // 100000
    int2*   csr      = (int2*)(ws0 + 300004);           // 2.5M floats
    bf16_t* rbuf     = (bf16_t*)(ws0 + 2800004);        // N*64 bf16 = 3.2M floats
    float*  aggbuf   = ws0 + 6000004;                   // N*64 fp32 = 6.4M floats
    float*  stats    = aggbuf + (size_t)N_NODES * 64;   // 3*1024
    float*  pooled   = stats + 3 * 1024;                // 16384
    int*    gcount   = (int*)(pooled + NGRAPH * 64);    // 256
    // transient CSR-build aliases inside aggbuf (all dead before gather#1 writes it)
    float* dinv      = aggbuf;                          // 100000
    int*   counts    = (int*)(aggbuf + 100000);         // 100000
    int*   cursor    = (int*)(aggbuf + 200000);         // 100000
    int*   blocksums = (int*)(aggbuf + 300000);         // 512

    const int nblk_e = (N_EDGES + 255) / 256;        // 4883
    const int nblk_g64 = N_NODES * 64 / 256;         // 25000
    const int nblk_seg = N_NODES / 4;                // 25000 (wave per node)
    const int nblk_mm = N_NODES / 32;                // 3125

    // zero counts and stats+pooled+gcount
    hipMemsetAsync(counts, 0, 100000 * sizeof(int), stream);
    hipMemsetAsync(stats, 0, (3 * 1024 + NGRAPH * 64 + NGRAPH) * sizeof(float), stream);

    // ---- CSR build: hist -> scan -> fill(s,w) -> segment degrees -> rescale ----
    k_hist<<<nblk_e, 256, 0, stream>>>(dst, counts);
    k_blockreduce<<<NBLK_SCAN, 256, 0, stream>>>(counts, blocksums);
    k_scanblocksums<<<1, 512, 0, stream>>>(blocksums);
    k_blockscan<<<NBLK_SCAN, 256, 0, stream>>>(counts, blocksums, offsets, cursor);
    k_fill<<<nblk_e, 256, 0, stream>>>(src, dst, (const float2*)edge_attr, cursor, csr);
    k_segnorm<<<nblk_seg, 256, 0, stream>>>(offsets, csr, dinv, selfnorm);
    k_rescale<<<nblk_seg, 256, 0, stream>>>(offsets, csr, dinv, selfnorm, dvec);

    // ---- layer 0: fused agg8 + mm0 -> r0 (bf16) + stats0 ----
    k_aggmm0<<<nblk_mm, 256, 0, stream>>>(x, offsets, csr, selfnorm, W0, b0, rbuf, stats);

    // ---- layer 1: gather + mm -> r1 (bf16) + stats1 ----
    k_gather64<<<nblk_g64, 256, 0, stream>>>(rbuf, offsets, csr, selfnorm, aggbuf);
    k_mm1<<<nblk_mm, 256, 0, stream>>>(aggbuf, dvec, stats, gammas, betas,
                                       Ws, bs, rbuf, stats + 1024);

    // ---- layer 2: gather + mm with fused pooling (r2 stays on-chip) ----
    k_gather64<<<nblk_g64, 256, 0, stream>>>(rbuf, offsets, csr, selfnorm, aggbuf);
    k_mm2<<<nblk_mm, 256, 0, stream>>>(aggbuf, dvec, stats + 1024, gammas + 64, betas + 64,
                                       Ws + 64 * 64, bs + 64, batch, pooled, gcount,
                                       stats + 2048);

    // ---- head ----
    k_head<<<NGRAPH, 64, 0, stream>>>(pooled, gcount, stats + 2048,
                                      gammas + 2 * 64, betas + 2 * 64,
                                      lin1_w, lin1_b, lin2_w, lin2_b, out);
}

// Round 10
// 444.066 us; speedup vs baseline: 2.1963x; 1.1626x over previous
//
#include <hip/hip_runtime.h>
#include <math.h>

#define N_NODES 100000
#define N_EDGES 1250000
#define NGRAPH 256
#define IN_DIM 8
#define DIM 64
#define BN_EPS 1e-5f

#define BSHIFT 11
#define BNODES 2048
#define NBUCK 49            // ceil(100000 / 2048)
#define NBLK_B 512
#define CHUNK 2442          // ceil(1250000 / 512)

typedef unsigned short bf16_t;

static __device__ inline float bf2f(bf16_t u) {
    return __uint_as_float(((unsigned int)u) << 16);
}
static __device__ inline bf16_t f2bf(float f) {
    unsigned int b = __float_as_uint(f);
    b += 0x7fffu + ((b >> 16) & 1u);
    return (bf16_t)(b >> 16);
}

// ---------------- coarse bucket histogram (49 buckets, LDS-binned) ----------------

__global__ void __launch_bounds__(256) k_bhist(const int* __restrict__ dst,
                                               int* __restrict__ bucket_count) {
    __shared__ int lh[NBUCK];
    int tid = threadIdx.x;
    if (tid < NBUCK) lh[tid] = 0;
    __syncthreads();
    int e0 = blockIdx.x * CHUNK;
    int e1 = e0 + CHUNK; if (e1 > N_EDGES) e1 = N_EDGES;
    for (int e = e0 + tid; e < e1; e += 256)
        atomicAdd(&lh[dst[e] >> BSHIFT], 1);
    __syncthreads();
    if (tid < NBUCK) atomicAdd(&bucket_count[tid], lh[tid]);
}

// ---------------- bucket base scan (49 entries, trivial) ----------------

__global__ void k_bscan(const int* __restrict__ bucket_count, int* __restrict__ bucket_base,
                        int* __restrict__ bucket_cursor, int* __restrict__ offsets) {
    if (threadIdx.x == 0) {
        int acc = 0;
        for (int b = 0; b < NBUCK; ++b) {
            bucket_base[b] = acc;
            bucket_cursor[b] = acc;
            acc += bucket_count[b];
        }
        offsets[N_NODES] = N_EDGES;
    }
}

// ------- bucket fill: per-block LDS count -> contiguous chunk reservation -> burst writes -------

__global__ void __launch_bounds__(256) k_bfill(const int* __restrict__ src,
                                               const int* __restrict__ dst,
                                               const float2* __restrict__ edge_attr,
                                               int* __restrict__ bucket_cursor,
                                               int2* __restrict__ ebuf) {
    __shared__ int lh[NBUCK], lbase[NBUCK];
    int tid = threadIdx.x;
    if (tid < NBUCK) lh[tid] = 0;
    __syncthreads();
    int e0 = blockIdx.x * CHUNK;
    int e1 = e0 + CHUNK; if (e1 > N_EDGES) e1 = N_EDGES;
    for (int e = e0 + tid; e < e1; e += 256)
        atomicAdd(&lh[dst[e] >> BSHIFT], 1);
    __syncthreads();
    if (tid < NBUCK) {
        lbase[tid] = atomicAdd(&bucket_cursor[tid], lh[tid]);
        lh[tid] = 0;
    }
    __syncthreads();
    for (int e = e0 + tid; e < e1; e += 256) {
        int d = dst[e];
        int b = d >> BSHIFT;
        int pos = lbase[b] + atomicAdd(&lh[b], 1);
        int pk = src[e] | ((d & (BNODES - 1)) << 17);  // src<2^17, dlocal<2^11
        ebuf[pos] = make_int2(pk, __float_as_int(edge_attr[e].y));
    }
}

// ------- bucket sort: exact CSR placement + offsets + dinv/selfnorm, all LDS-local -------
// one block per bucket; scattered writes confined to a ~200KB single-XCD region.

__global__ void __launch_bounds__(512) k_bsort(
        const int* __restrict__ bucket_base, const int2* __restrict__ ebuf,
        int* __restrict__ offsets, int2* __restrict__ csr,
        float* __restrict__ dinv, float* __restrict__ selfnorm) {
    __shared__ int cnt[BNODES];
    __shared__ float wsum[BNODES];
    __shared__ int loff[BNODES];
    __shared__ int tsum[512];
    int tid = threadIdx.x;
    int b = blockIdx.x;
    int nbase = b * BNODES;
    int nend = nbase + BNODES; if (nend > N_NODES) nend = N_NODES;
    int nloc = nend - nbase;
    for (int i = tid; i < BNODES; i += 512) { cnt[i] = 0; wsum[i] = 0.0f; }
    __syncthreads();
    int e0 = bucket_base[b];
    int e1 = (b + 1 < NBUCK) ? bucket_base[b + 1] : N_EDGES;
    for (int e = e0 + tid; e < e1; e += 512) {
        int2 p = ebuf[e];
        int dl = p.x >> 17;
        atomicAdd(&cnt[dl], 1);
        atomicAdd(&wsum[dl], __int_as_float(p.y));
    }
    __syncthreads();
    // exclusive scan over 2048 counts: 4 per thread + 512-ladder
    int b4 = tid * 4;
    int c0 = cnt[b4], c1 = cnt[b4 + 1], c2 = cnt[b4 + 2], c3 = cnt[b4 + 3];
    tsum[tid] = c0 + c1 + c2 + c3;
    __syncthreads();
    for (int off = 1; off < 512; off <<= 1) {
        int add = (tid >= off) ? tsum[tid - off] : 0;
        __syncthreads();
        tsum[tid] += add;
        __syncthreads();
    }
    int excl = tsum[tid] - (c0 + c1 + c2 + c3);
    loff[b4] = excl;
    loff[b4 + 1] = excl + c0;
    loff[b4 + 2] = excl + c0 + c1;
    loff[b4 + 3] = excl + c0 + c1 + c2;
    __syncthreads();
    for (int i = tid; i < nloc; i += 512) {
        offsets[nbase + i] = e0 + loff[i];
        float r = rsqrtf(wsum[i] + 1.0f);  // +1 = self-loop weight
        dinv[nbase + i] = r;
        selfnorm[nbase + i] = r * r;
    }
    for (int i = tid; i < BNODES; i += 512) cnt[i] = loff[i];  // cursor
    __syncthreads();
    for (int e = e0 + tid; e < e1; e += 512) {
        int2 p = ebuf[e];
        int dl = p.x >> 17;
        int pos = e0 + atomicAdd(&cnt[dl], 1);
        csr[pos] = make_int2(p.x & 0x1FFFF, p.y);
    }
}

// ------- rescale csr in place: w -> nv = dinv[s]*w*dinv[d]; emit dvec row-sums -------

__global__ void __launch_bounds__(256) k_rescale(
        const int* __restrict__ offsets, int2* __restrict__ csr,
        const float* __restrict__ dinv, const float* __restrict__ selfnorm,
        float* __restrict__ dvec) {
    int wid = (blockIdx.x * 256 + threadIdx.x) >> 6;
    int lane = threadIdx.x & 63;
    if (wid >= N_NODES) return;
    int e0 = offsets[wid], e1 = offsets[wid + 1];
    float dvd = dinv[wid];
    float part = 0.0f;
    for (int e = e0 + lane; e < e1; e += 64) {
        int2 p = csr[e];
        float nv = dinv[p.x] * __int_as_float(p.y) * dvd;
        csr[e] = make_int2(p.x, __float_as_int(nv));
        part += nv;
    }
#pragma unroll
    for (int off = 32; off > 0; off >>= 1) part += __shfl_xor(part, off, 64);
    if (lane == 0) dvec[wid] = selfnorm[wid] + part;
}

// ------- fused layer 0: agg (8ch) + matmul 8x64 + relu + stats -------

__global__ void __launch_bounds__(256) k_aggmm0(
        const float* __restrict__ x, const int* __restrict__ offsets,
        const int2* __restrict__ csr, const float* __restrict__ selfnorm,
        const float* __restrict__ W0, const float* __restrict__ b0,
        bf16_t* __restrict__ rout, float* __restrict__ stats) {
    __shared__ float Wsh[IN_DIM * 64];
    __shared__ float bsh[64];
    __shared__ float sstat[64], sq[64];
    int tid = threadIdx.x;
    for (int i = tid; i < IN_DIM * 64; i += 256) Wsh[i] = W0[i];
    if (tid < 64) { bsh[tid] = b0[tid]; sstat[tid] = 0.0f; sq[tid] = 0.0f; }
    __syncthreads();
    int node = blockIdx.x * 32 + (tid >> 3);
    int ch = tid & 7;
    float acc = selfnorm[node] * x[node * 8 + ch];
    int e0 = offsets[node], e1 = offsets[node + 1];
    for (int base = e0; base < e1; base += 8) {
        int n = e1 - base;
        n = (n > 8) ? 8 : n;
        int2 pe = (ch < n) ? csr[base + ch] : make_int2(node, 0);
        int s[8];
        float w[8], v[8];
#pragma unroll
        for (int u = 0; u < 8; ++u) {
            s[u] = __shfl(pe.x, u, 8);
            w[u] = __int_as_float(__shfl(pe.y, u, 8));
        }
#pragma unroll
        for (int u = 0; u < 8; ++u) v[u] = x[s[u] * 8 + ch];
#pragma unroll
        for (int u = 0; u < 8; ++u) acc = fmaf(w[u], v[u], acc);
    }
    float a[8];
#pragma unroll
    for (int k = 0; k < 8; ++k) a[k] = __shfl(acc, k, 8);
    unsigned int pk[4];
#pragma unroll
    for (int q = 0; q < 4; ++q) {
        float v0, v1;
#pragma unroll
        for (int h = 0; h < 2; ++h) {
            int c = ch * 8 + 2 * q + h;
            float v = bsh[c];
#pragma unroll
            for (int k = 0; k < 8; ++k) v = fmaf(a[k], Wsh[k * 64 + c], v);
            v = fmaxf(v, 0.0f);
            atomicAdd(&sstat[c], v);
            atomicAdd(&sq[c], v * v);
            if (h == 0) v0 = v; else v1 = v;
        }
        pk[q] = (unsigned int)f2bf(v0) | ((unsigned int)f2bf(v1) << 16);
    }
    *(uint4*)(rout + node * 64 + ch * 8) = make_uint4(pk[0], pk[1], pk[2], pk[3]);
    __syncthreads();
    if (tid < 64) {
        int bin = blockIdx.x & 7;
        atomicAdd(&stats[bin * 128 + tid], sstat[tid]);
        atomicAdd(&stats[bin * 128 + 64 + tid], sq[tid]);
    }
}

// ------- 64-ch aggregation: lane-parallel CSR + 8-wide pipelined row loads -------

__global__ void __launch_bounds__(256) k_gather64(
        const bf16_t* __restrict__ t, const int* __restrict__ offsets,
        const int2* __restrict__ csr, const float* __restrict__ selfnorm,
        float* __restrict__ agg) {
    int wid = (blockIdx.x * 256 + threadIdx.x) >> 6;
    int lane = threadIdx.x & 63;
    if (wid >= N_NODES) return;
    float acc = selfnorm[wid] * bf2f(t[(size_t)wid * 64 + lane]);
    int e0 = offsets[wid], e1 = offsets[wid + 1];
    for (int base = e0; base < e1; base += 64) {
        int n = e1 - base;
        n = (n > 64) ? 64 : n;
        int2 pe = make_int2(wid, 0);  // pad: own row, weight 0
        if (lane < n) pe = csr[base + lane];
        int ng = (n + 7) >> 3;
        for (int g = 0; g < ng; ++g) {
            int j = g * 8;
            int s[8];
            float w[8];
#pragma unroll
            for (int u = 0; u < 8; ++u) {
                s[u] = __shfl(pe.x, j + u, 64);
                w[u] = __int_as_float(__shfl(pe.y, j + u, 64));
            }
            float v[8];
#pragma unroll
            for (int u = 0; u < 8; ++u) v[u] = bf2f(t[(size_t)s[u] * 64 + lane]);
#pragma unroll
            for (int u = 0; u < 8; ++u) acc = fmaf(w[u], v[u], acc);
        }
    }
    agg[(size_t)wid * 64 + lane] = acc;
}

// ------- mid layer matmul: r' = relu((AGG*sc + dvec*sh) @ W + b), bf16 out, stats -------

__global__ void __launch_bounds__(256) k_mm1(
        const float* __restrict__ agg, const float* __restrict__ dvec,
        const float* __restrict__ statsin, const float* __restrict__ gamma,
        const float* __restrict__ beta, const float* __restrict__ W,
        const float* __restrict__ bias, bf16_t* __restrict__ rout,
        float* __restrict__ statsout) {
    __shared__ float Wsh[64 * 64];
    __shared__ float hsh[32 * 64];
    __shared__ float scs[64], shs[64];
    __shared__ float s1[256], s2[256];
    int tid = threadIdx.x;
    if (tid < 64) {
        float s = 0.0f, q = 0.0f;
#pragma unroll
        for (int b = 0; b < 8; ++b) {
            s += statsin[b * 128 + tid];
            q += statsin[b * 128 + 64 + tid];
        }
        const float invn = 1.0f / (float)N_NODES;
        float mu = s * invn;
        float var = q * invn - mu * mu;
        float rs = rsqrtf(var + BN_EPS);
        float sc = gamma[tid] * rs;
        scs[tid] = sc;
        shs[tid] = beta[tid] - sc * mu;
    }
    {
        const float4* W4 = (const float4*)W;
        float4* Wsh4 = (float4*)Wsh;
        for (int i = tid; i < 1024; i += 256) Wsh4[i] = W4[i];
    }
    __syncthreads();
    int row0 = blockIdx.x * 32;
    {
        const float4* a4 = (const float4*)(agg + (size_t)row0 * 64);
        float4* h4 = (float4*)hsh;
        for (int i = tid; i < 512; i += 256) {
            float4 a = a4[i];
            int kk = (i * 4) & 63;
            int rr = (i * 4) >> 6;
            float dv = dvec[row0 + rr];
            h4[i] = make_float4(a.x * scs[kk] + dv * shs[kk],
                                a.y * scs[kk + 1] + dv * shs[kk + 1],
                                a.z * scs[kk + 2] + dv * shs[kk + 2],
                                a.w * scs[kk + 3] + dv * shs[kk + 3]);
        }
    }
    __syncthreads();
    int c = tid & 63, rsl = tid >> 6;
    float b_c = bias[c];
    float acc[8];
#pragma unroll
    for (int j = 0; j < 8; ++j) acc[j] = 0.0f;
    for (int k = 0; k < 64; k += 4) {
        float w0 = Wsh[(k + 0) * 64 + c];
        float w1 = Wsh[(k + 1) * 64 + c];
        float w2 = Wsh[(k + 2) * 64 + c];
        float w3 = Wsh[(k + 3) * 64 + c];
#pragma unroll
        for (int j = 0; j < 8; ++j) {
            float4 hv = *(const float4*)&hsh[(rsl * 8 + j) * 64 + k];
            acc[j] = fmaf(hv.x, w0, fmaf(hv.y, w1, fmaf(hv.z, w2, fmaf(hv.w, w3, acc[j]))));
        }
    }
    float sum = 0.0f, ssq = 0.0f;
#pragma unroll
    for (int j = 0; j < 8; ++j) {
        float v = fmaxf(acc[j] + b_c, 0.0f);
        rout[(size_t)(row0 + rsl * 8 + j) * 64 + c] = f2bf(v);
        sum += v;
        ssq += v * v;
    }
    s1[tid] = sum; s2[tid] = ssq;
    __syncthreads();
    if (tid < 64) {
        int bin = blockIdx.x & 7;
        atomicAdd(&statsout[bin * 128 + tid],
                  s1[tid] + s1[tid + 64] + s1[tid + 128] + s1[tid + 192]);
        atomicAdd(&statsout[bin * 128 + 64 + tid],
                  s2[tid] + s2[tid + 64] + s2[tid + 128] + s2[tid + 192]);
    }
}

// ------- final layer matmul + fused pooling: r2 never touches global memory -------

__global__ void __launch_bounds__(256) k_mm2(
        const float* __restrict__ agg, const float* __restrict__ dvec,
        const float* __restrict__ statsin, const float* __restrict__ gamma,
        const float* __restrict__ beta, const float* __restrict__ W,
        const float* __restrict__ bias, const int* __restrict__ batch,
        float* __restrict__ pooled, int* __restrict__ gcount,
        float* __restrict__ statsout) {
    __shared__ float Wsh[64 * 64];
    __shared__ float hsh[32 * 64];
    __shared__ float rt[32 * 64];
    __shared__ float scs[64], shs[64];
    __shared__ float s1[256], s2[256];
    __shared__ int sbatch[32];
    int tid = threadIdx.x;
    int row0 = blockIdx.x * 32;
    if (tid < 64) {
        float s = 0.0f, q = 0.0f;
#pragma unroll
        for (int b = 0; b < 8; ++b) {
            s += statsin[b * 128 + tid];
            q += statsin[b * 128 + 64 + tid];
        }
        const float invn = 1.0f / (float)N_NODES;
        float mu = s * invn;
        float var = q * invn - mu * mu;
        float rs = rsqrtf(var + BN_EPS);
        float sc = gamma[tid] * rs;
        scs[tid] = sc;
        shs[tid] = beta[tid] - sc * mu;
    }
    if (tid >= 64 && tid < 96) sbatch[tid - 64] = batch[row0 + tid - 64];
    {
        const float4* W4 = (const float4*)W;
        float4* Wsh4 = (float4*)Wsh;
        for (int i = tid; i < 1024; i += 256) Wsh4[i] = W4[i];
    }
    __syncthreads();
    {
        const float4* a4 = (const float4*)(agg + (size_t)row0 * 64);
        float4* h4 = (float4*)hsh;
        for (int i = tid; i < 512; i += 256) {
            float4 a = a4[i];
            int kk = (i * 4) & 63;
            int rr = (i * 4) >> 6;
            float dv = dvec[row0 + rr];
            h4[i] = make_float4(a.x * scs[kk] + dv * shs[kk],
                                a.y * scs[kk + 1] + dv * shs[kk + 1],
                                a.z * scs[kk + 2] + dv * shs[kk + 2],
                                a.w * scs[kk + 3] + dv * shs[kk + 3]);
        }
    }
    __syncthreads();
    int c = tid & 63, rsl = tid >> 6;
    float b_c = bias[c];
    float acc[8];
#pragma unroll
    for (int j = 0; j < 8; ++j) acc[j] = 0.0f;
    for (int k = 0; k < 64; k += 4) {
        float w0 = Wsh[(k + 0) * 64 + c];
        float w1 = Wsh[(k + 1) * 64 + c];
        float w2 = Wsh[(k + 2) * 64 + c];
        float w3 = Wsh[(k + 3) * 64 + c];
#pragma unroll
        for (int j = 0; j < 8; ++j) {
            float4 hv = *(const float4*)&hsh[(rsl * 8 + j) * 64 + k];
            acc[j] = fmaf(hv.x, w0, fmaf(hv.y, w1, fmaf(hv.z, w2, fmaf(hv.w, w3, acc[j]))));
        }
    }
    float sum = 0.0f, ssq = 0.0f;
#pragma unroll
    for (int j = 0; j < 8; ++j) {
        float v = fmaxf(acc[j] + b_c, 0.0f);
        rt[(rsl * 8 + j) * 64 + c] = v;
        sum += v;
        ssq += v * v;
    }
    s1[tid] = sum; s2[tid] = ssq;
    __syncthreads();
    if (tid < 64) {
        int cur = sbatch[0], cnt = 0;
        float a = 0.0f;
        for (int r = 0; r < 32; ++r) {
            int g = sbatch[r];
            if (g != cur) {
                atomicAdd(&pooled[cur * 64 + c], a);
                if (c == 0) atomicAdd(&gcount[cur], cnt);
                cur = g; a = 0.0f; cnt = 0;
            }
            a += rt[r * 64 + c];
            cnt += 1;
        }
        atomicAdd(&pooled[cur * 64 + c], a);
        if (c == 0) atomicAdd(&gcount[cur], cnt);
        int bin = blockIdx.x & 7;
        atomicAdd(&statsout[bin * 128 + tid],
                  s1[tid] + s1[tid + 64] + s1[tid + 128] + s1[tid + 192]);
        atomicAdd(&statsout[bin * 128 + 64 + tid],
                  s2[tid] + s2[tid + 64] + s2[tid + 128] + s2[tid + 192]);
    }
}

// ------- head: BN affine from binned stats folded via counts, mlp, log_softmax -------

__global__ void k_head(const float* __restrict__ pooled, const int* __restrict__ gcount,
                       const float* __restrict__ stats, const float* __restrict__ gamma,
                       const float* __restrict__ beta, const float* __restrict__ w1,
                       const float* __restrict__ b1, const float* __restrict__ w2,
                       const float* __restrict__ b2, float* __restrict__ out) {
    __shared__ float p[64];
    __shared__ float hid[64];
    __shared__ float o[2];
    int g = blockIdx.x, c = threadIdx.x;
    float s = 0.0f, q = 0.0f;
#pragma unroll
    for (int b = 0; b < 8; ++b) {
        s += stats[b * 128 + c];
        q += stats[b * 128 + 64 + c];
    }
    const float invn = 1.0f / (float)N_NODES;
    float mu = s * invn;
    float var = q * invn - mu * mu;
    float rs = rsqrtf(var + BN_EPS);
    float sc = gamma[c] * rs;
    float sh = beta[c] - sc * mu;
    p[c] = sc * pooled[g * 64 + c] + (float)gcount[g] * sh;
    __syncthreads();
    float acc = b1[c];
#pragma unroll
    for (int k = 0; k < 64; ++k) acc += p[k] * w1[k * 64 + c];
    hid[c] = fmaxf(acc, 0.0f);
    __syncthreads();
    if (c < 2) {
        float a = b2[c];
#pragma unroll
        for (int k = 0; k < 64; ++k) a += hid[k] * w2[k * 2 + c];
        o[c] = a;
    }
    __syncthreads();
    if (c == 0) {
        float m = fmaxf(o[0], o[1]);
        float l = m + logf(expf(o[0] - m) + expf(o[1] - m));
        out[g * 2 + 0] = o[0] - l;
        out[g * 2 + 1] = o[1] - l;
    }
}

extern "C" void kernel_launch(void* const* d_in, const int* in_sizes, int n_in,
                              void* d_out, int out_size, void* d_ws, size_t ws_size,
                              hipStream_t stream) {
    const float* x        = (const float*)d_in[0];
    const int*   ei       = (const int*)d_in[1];
    const int*   batch    = (const int*)d_in[2];
    const float* edge_attr= (const float*)d_in[3];
    const float* W0       = (const float*)d_in[4];
    const float* b0       = (const float*)d_in[5];
    const float* Ws       = (const float*)d_in[6];
    const float* bs       = (const float*)d_in[7];
    const float* gammas   = (const float*)d_in[8];
    const float* betas    = (const float*)d_in[9];
    const float* lin1_w   = (const float*)d_in[10];
    const float* lin1_b   = (const float*)d_in[11];
    const float* lin2_w   = (const float*)d_in[12];
    const float* lin2_b   = (const float*)d_in[13];
    float* out = (float*)d_out;

    const int* src = ei;
    const int* dst = ei + N_EDGES;

    // workspace layout (float units)
    float*  ws0      = (float*)d_ws;
    float*  selfnorm = ws0;                             // 100000
    int*    offsets  = (int*)(ws0 + 100000);            // 100001, pad to 100004
    float*  dvec     = ws0 + 200004;                    // 100000
    int2*   csr      = (int2*)(ws0 + 300004);           // 2.5M floats
    bf16_t* rbuf     = (bf16_t*)(ws0 + 2800004);        // N*64 bf16 = 3.2M floats
    float*  aggbuf   = ws0 + 6000004;                   // N*64 fp32 = 6.4M floats
    float*  stats    = aggbuf + (size_t)N_NODES * 64;   // 3*1024
    float*  pooled   = stats + 3 * 1024;                // 16384
    int*    gcount   = (int*)(pooled + NGRAPH * 64);    // 256
    // transient CSR-build aliases inside aggbuf (all dead before gather#1 writes it)
    float* dinv          = aggbuf;                      // 100000
    int*   bucket_count  = (int*)(aggbuf + 100000);     // 64
    int*   bucket_base   = (int*)(aggbuf + 100064);     // 64
    int*   bucket_cursor = (int*)(aggbuf + 100128);     // 64
    int2*  ebuf          = (int2*)(aggbuf + 200000);    // 2.5M floats

    const int nblk_g64 = N_NODES * 64 / 256;         // 25000
    const int nblk_seg = N_NODES / 4;                // 25000 (wave per node)
    const int nblk_mm = N_NODES / 32;                // 3125

    hipMemsetAsync(bucket_count, 0, 64 * sizeof(int), stream);
    hipMemsetAsync(stats, 0, (3 * 1024 + NGRAPH * 64 + NGRAPH) * sizeof(float), stream);

    // ---- CSR build: bucket hist -> scan -> bucket fill -> in-bucket sort -> rescale ----
    k_bhist<<<NBLK_B, 256, 0, stream>>>(dst, bucket_count);
    k_bscan<<<1, 64, 0, stream>>>(bucket_count, bucket_base, bucket_cursor, offsets);
    k_bfill<<<NBLK_B, 256, 0, stream>>>(src, dst, (const float2*)edge_attr,
                                        bucket_cursor, ebuf);
    k_bsort<<<NBUCK, 512, 0, stream>>>(bucket_base, ebuf, offsets, csr, dinv, selfnorm);
    k_rescale<<<nblk_seg, 256, 0, stream>>>(offsets, csr, dinv, selfnorm, dvec);

    // ---- layer 0: fused agg8 + mm0 -> r0 (bf16) + stats0 ----
    k_aggmm0<<<nblk_mm, 256, 0, stream>>>(x, offsets, csr, selfnorm, W0, b0, rbuf, stats);

    // ---- layer 1: gather + mm -> r1 (bf16) + stats1 ----
    k_gather64<<<nblk_g64, 256, 0, stream>>>(rbuf, offsets, csr, selfnorm, aggbuf);
    k_mm1<<<nblk_mm, 256, 0, stream>>>(aggbuf, dvec, stats, gammas, betas,
                                       Ws, bs, rbuf, stats + 1024);

    // ---- layer 2: gather + mm with fused pooling (r2 stays on-chip) ----
    k_gather64<<<nblk_g64, 256, 0, stream>>>(rbuf, offsets, csr, selfnorm, aggbuf);
    k_mm2<<<nblk_mm, 256, 0, stream>>>(aggbuf, dvec, stats + 1024, gammas + 64, betas + 64,
                                       Ws + 64 * 64, bs + 64, batch, pooled, gcount,
                                       stats + 2048);

    // ---- head ----
    k_head<<<NGRAPH, 64, 0, stream>>>(pooled, gcount, stats + 2048,
                                      gammas + 2 * 64, betas + 2 * 64,
                                      lin1_w, lin1_b, lin2_w, lin2_b, out);
}